// Round 10
// baseline (389.546 us; speedup 1.0000x reference)
//
#include <hip/hip_runtime.h>
#include <hip/hip_bf16.h>

#define DIV_UP(a, b) (((a) + (b) - 1) / (b))
typedef long long ll;

// ---------- runtime-dtype helpers ----------
__device__ __forceinline__ float ldf(const void* p, ll i, int bf) {
    return bf ? __bfloat162float(((const __hip_bfloat16*)p)[i]) : ((const float*)p)[i];
}
__device__ __forceinline__ int ldi(const int* p, ll i, int w) {
    return w ? p[2 * i] : p[i];
}
template <bool BF16>
__device__ __forceinline__ float ldx(const void* p, ll i) {
    return BF16 ? __bfloat162float(((const __hip_bfloat16*)p)[i]) : ((const float*)p)[i];
}
template <bool BF16>
__device__ __forceinline__ void stf(void* p, ll i, float v) {
    if (BF16)
        ((__hip_bfloat16*)p)[i] = __float2bfloat16(v);
    else
        ((float*)p)[i] = v;
}
// MODE: 0 = f32, 1 = bf16 (compile-time), 2 = external (runtime bf flag)
template <int MODE>
__device__ __forceinline__ float ldm(const void* p, ll i, int bf) {
    if (MODE == 0) return ((const float*)p)[i];
    if (MODE == 1) return __bfloat162float(((const __hip_bfloat16*)p)[i]);
    return ldf(p, i, bf);
}

// ---- ordered-uint encoding for float atomicMax ----
__device__ __forceinline__ unsigned fenc(float f) {
    unsigned u = __float_as_uint(f);
    return (u & 0x80000000u) ? ~u : (u | 0x80000000u);
}
__device__ __forceinline__ float fdec(unsigned u) {
    unsigned v = (u & 0x80000000u) ? (u & 0x7FFFFFFFu) : ~u;
    return __uint_as_float(v);
}
#define ENC_NEG_INF 0x007FFFFFu

// ---- grouped f32 weight pool offsets (elements) ----
// Layer GEMM weights are regrouped as Wg[group][k][OGP] (OGP floats per k, zero-padded),
// so a wave's W reads are uniform float4 addresses -> scalar s_load into SGPRs.
#define G1W 0        // 8 groups x 36 k x 12 = 3456   (W1 36->75, OG=10)
#define G1B 3456     // 8 x 12 = 96
#define G2W 3552     // 16 x 75 x 12 = 14400          (W2 75->150, OG=10)
#define G2B 17952    // 16 x 12 = 192
#define G3W 18144    // 4 x 150 x 16 = 9600           (W3 150->50, OG=13)
#define G3B 27744    // 4 x 16 = 64 (zeros, unused)
#define OHW 27808    // Wo 150
#define OHB3 27958   // b3 50
#define OHBO 28008   // bo 3
#define N_WF2 28011

// ---------------- dtype detection (parallel, 1 block x 256) ----------------
__global__ void k_detect(const unsigned* __restrict__ xb, const unsigned* __restrict__ eb,
                         int* __restrict__ flags) {
    __shared__ int sv[2];
    int t = threadIdx.x;
    if (t < 2) sv[t] = 0;
    __syncthreads();
    unsigned e = (xb[t] >> 7) & 0xFFu;
    int vote = (e >= 115u && e <= 133u) ? 1 : 0;
    int zero = (eb[2 * t + 1] == 0u) ? 1 : 0;
    atomicAdd(&sv[0], vote);
    atomicAdd(&sv[1], zero);
    __syncthreads();
    if (t == 0) {
        flags[0] = (sv[0] > 128) ? 1 : 0;
        flags[1] = (sv[1] > 200) ? 1 : 0;
    }
}

// ---------------- convert + regroup all weights/biases into f32 pool ----------------
__global__ void k_cvt(const void* __restrict__ W1, const void* __restrict__ b1,
                      const void* __restrict__ W2, const void* __restrict__ b2,
                      const void* __restrict__ W3, const void* __restrict__ b3,
                      const void* __restrict__ Wo, const void* __restrict__ bo,
                      float* __restrict__ wf, const int* __restrict__ flags) {
    int t = blockIdx.x * blockDim.x + threadIdx.x;
    if (t >= N_WF2) return;
    int bf = flags[0];
    float v = 0.0f;
    if (t < G1B) {  // W1 grouped: g*10+j of 75, k of 36
        int r = t;
        int g = r / 432;
        r -= g * 432;
        int k = r / 12, j = r - k * 12;
        int o = g * 10 + j;
        if (j < 10 && o < 75) v = ldf(W1, k * 75 + o, bf);
    } else if (t < G2W) {  // b1 grouped
        int r = t - G1B;
        int g = r / 12, j = r - g * 12;
        int o = g * 10 + j;
        if (j < 10 && o < 75) v = ldf(b1, o, bf);
    } else if (t < G2B) {  // W2 grouped: g*10+j of 150, k of 75
        int r = t - G2W;
        int g = r / 900;
        r -= g * 900;
        int k = r / 12, j = r - k * 12;
        int o = g * 10 + j;
        if (j < 10 && o < 150) v = ldf(W2, k * 150 + o, bf);
    } else if (t < G3W) {  // b2 grouped
        int r = t - G2B;
        int g = r / 12, j = r - g * 12;
        int o = g * 10 + j;
        if (j < 10 && o < 150) v = ldf(b2, o, bf);
    } else if (t < G3B) {  // W3 grouped: g*13+j of 50, k of 150, OGP=16
        int r = t - G3W;
        int g = r / 2400;
        r -= g * 2400;
        int k = r / 16, j = r - k * 16;
        int o = g * 13 + j;
        if (j < 13 && o < 50) v = ldf(W3, k * 50 + o, bf);
    } else if (t < OHW) {
        v = 0.0f;  // b3-group pad (unused)
    } else if (t < OHB3) {
        v = ldf(Wo, t - OHW, bf);
    } else if (t < OHBO) {
        v = ldf(b3, t - OHB3, bf);
    } else {
        v = ldf(bo, t - OHBO, bf);
    }
    wf[t] = v;
}

// ---------------- CSR build ----------------
__global__ void k_zero(int* p, int n) {
    int t = blockIdx.x * blockDim.x + threadIdx.x;
    if (t < n) p[t] = 0;
}
__global__ void k_hist(const int* __restrict__ ei, int* __restrict__ cnt,
                       const int* __restrict__ flags, int E) {
    int t = blockIdx.x * blockDim.x + threadIdx.x;
    if (t >= E) return;
    atomicAdd(&cnt[ldi(ei, (ll)E + t, flags[1])], 1);
}

// ---------------- multi-block exclusive scan over M=N+1 values ----------------
__global__ void k_scan1(const int* __restrict__ cnt, int* __restrict__ bsum,
                        float* __restrict__ dinv, int N) {
    __shared__ int s[256];
    int t = threadIdx.x;
    int idx = blockIdx.x * 256 + t;
    int v = (idx < N) ? cnt[idx] : 0;
    if (idx < N) dinv[idx] = rsqrtf((float)v + 1.0f);  // +1 self-loop
    s[t] = v;
    __syncthreads();
#pragma unroll
    for (int off = 128; off > 0; off >>= 1) {
        if (t < off) s[t] += s[t + off];
        __syncthreads();
    }
    if (t == 0) bsum[blockIdx.x] = s[0];
}
__global__ void k_scan2(int* __restrict__ bsum, int nb) {
    __shared__ int s[256];
    int t = threadIdx.x;
    int run = 0;
    for (int base = 0; base < nb; base += 256) {
        int i = base + t;
        int v = (i < nb) ? bsum[i] : 0;
        s[t] = v;
        __syncthreads();
        for (int off = 1; off < 256; off <<= 1) {
            int o = (t >= off) ? s[t - off] : 0;
            __syncthreads();
            s[t] += o;
            __syncthreads();
        }
        if (i < nb) bsum[i] = run + s[t] - v;
        run += s[255];
        __syncthreads();
    }
}
__global__ void k_scan3(const int* __restrict__ cnt, const int* __restrict__ bsum,
                        int* __restrict__ rowptr, int N) {
    __shared__ int s[256];
    int t = threadIdx.x;
    int idx = blockIdx.x * 256 + t;
    int v = (idx < N) ? cnt[idx] : 0;
    s[t] = v;
    __syncthreads();
    for (int off = 1; off < 256; off <<= 1) {
        int o = (t >= off) ? s[t - off] : 0;
        __syncthreads();
        s[t] += o;
        __syncthreads();
    }
    if (idx <= N) rowptr[idx] = bsum[blockIdx.x] + s[t] - v;
}

// fill interleaved (src, weight) pairs
__global__ void k_fill(const int* __restrict__ ei, const int* __restrict__ rowptr,
                       int* __restrict__ cursor, int2* __restrict__ ep,
                       const float* __restrict__ dinv, const int* __restrict__ flags, int E) {
    int t = blockIdx.x * blockDim.x + threadIdx.x;
    if (t >= E) return;
    int wi = flags[1];
    int s = ldi(ei, t, wi);
    int d = ldi(ei, (ll)E + t, wi);
    int pos = rowptr[d] + atomicAdd(&cursor[d], 1);
    int2 v;
    v.x = s;
    v.y = __float_as_int(dinv[s] * dinv[d]);
    ep[pos] = v;
}

// ---------------- CSR aggregation: Y[n] = dinv[n]^2*X[n] + sum_e w_e * X[src_e] ----------------
// wave per node; C <= 128; MODE selects X dtype (0 f32 / 1 bf16 / 2 runtime)
template <int MODE>
__global__ void k_agg(const void* __restrict__ X, int xstride, float* __restrict__ Y, int ystride,
                      int C, const int* __restrict__ rowptr, const int2* __restrict__ ep,
                      const float* __restrict__ dinv, const int* __restrict__ flags, int N) {
    int n = blockIdx.x * 4 + (threadIdx.x >> 6);
    if (n >= N) return;
    int lane = threadIdx.x & 63;
    int bf = (MODE == 2) ? flags[0] : 0;
    float di = dinv[n];
    float w0 = di * di;
    int c1 = lane + 64;
    bool has0 = lane < C, has1 = c1 < C;
    float a0 = has0 ? w0 * ldm<MODE>(X, (ll)n * xstride + lane, bf) : 0.0f;
    float a1 = has1 ? w0 * ldm<MODE>(X, (ll)n * xstride + c1, bf) : 0.0f;
    int j = rowptr[n];
    int je = rowptr[n + 1];
    for (; j + 3 < je; j += 4) {
        int2 v0 = ep[j];
        int2 v1 = ep[j + 1];
        int2 v2 = ep[j + 2];
        int2 v3 = ep[j + 3];
        float wa = __int_as_float(v0.y), wb = __int_as_float(v1.y);
        float wc = __int_as_float(v2.y), wd = __int_as_float(v3.y);
        if (has0) {
            float x0 = ldm<MODE>(X, (ll)v0.x * xstride + lane, bf);
            float x1 = ldm<MODE>(X, (ll)v1.x * xstride + lane, bf);
            float x2 = ldm<MODE>(X, (ll)v2.x * xstride + lane, bf);
            float x3 = ldm<MODE>(X, (ll)v3.x * xstride + lane, bf);
            a0 = fmaf(wa, x0, a0);
            a0 = fmaf(wb, x1, a0);
            a0 = fmaf(wc, x2, a0);
            a0 = fmaf(wd, x3, a0);
        }
        if (has1) {
            float x0 = ldm<MODE>(X, (ll)v0.x * xstride + c1, bf);
            float x1 = ldm<MODE>(X, (ll)v1.x * xstride + c1, bf);
            float x2 = ldm<MODE>(X, (ll)v2.x * xstride + c1, bf);
            float x3 = ldm<MODE>(X, (ll)v3.x * xstride + c1, bf);
            a1 = fmaf(wa, x0, a1);
            a1 = fmaf(wb, x1, a1);
            a1 = fmaf(wc, x2, a1);
            a1 = fmaf(wd, x3, a1);
        }
    }
    for (; j < je; ++j) {
        int2 v0 = ep[j];
        float wa = __int_as_float(v0.y);
        if (has0) a0 = fmaf(wa, ldm<MODE>(X, (ll)v0.x * xstride + lane, bf), a0);
        if (has1) a1 = fmaf(wa, ldm<MODE>(X, (ll)v0.x * xstride + c1, bf), a1);
    }
    if (has0) Y[(ll)n * ystride + lane] = a0;
    if (has1) Y[(ll)n * ystride + c1] = a1;
}

// ---------------- wave-uniform-W GEMM: Y = act(X @ W + b) ----------------
// lane = node, wave = output group of OG cols. W reads are wave-uniform (grouped pool,
// readfirstlane'd group id) -> scalar s_loads feeding v_fma's SGPR operand: zero LDS for W.
// X staged once as transposed tile Xs[K][65] (+1 pad: stage-writes and Xs[k][lane] reads are
// both consecutive-bank, conflict-free). Per k-step per wave: 1 ds_read_b32 + OG FMA.
// R9 lesson: per-lane W reads from LDS are 16x wave-redundant broadcast - structural waste.
template <int K, int OUT, int OG, int OGP, bool RELU, bool BIAS, bool BF16_IN, bool BF16_OUT>
__global__ __launch_bounds__(256) void k_gemm(const void* __restrict__ Xv, int xstride,
                                              void* __restrict__ Yv, int ystride,
                                              const float* __restrict__ Wgp,
                                              const float* __restrict__ bgp, int N) {
    __shared__ float Xs[K][65];
    const int tid = threadIdx.x;
    const int lane = tid & 63;
    const int node0 = blockIdx.x * 64;
    // stage X tile (64 nodes x K), transposed; coalesced global reads (consecutive idx =
    // consecutive k within a node row). Unguarded node overread -> ws pad region.
    for (int idx = tid; idx < 64 * K; idx += 256) {
        int nl = idx / K;
        int k = idx - nl * K;
        Xs[k][nl] = ldx<BF16_IN>(Xv, (ll)(node0 + nl) * xstride + k);
    }
    const int g = __builtin_amdgcn_readfirstlane((int)blockIdx.y * 4 + (tid >> 6));
    const float* Wr = Wgp + (ll)g * K * OGP;
    float acc[OG];
#pragma unroll
    for (int j = 0; j < OG; ++j) acc[j] = 0.0f;
    __syncthreads();
#pragma unroll 4
    for (int k = 0; k < K; ++k) {
        float xv = Xs[k][lane];
        const float4* w4 = (const float4*)(Wr + k * OGP);
        float w[OGP];
#pragma unroll
        for (int q = 0; q < OGP / 4; ++q) ((float4*)w)[q] = w4[q];
#pragma unroll
        for (int j = 0; j < OG; ++j) acc[j] = fmaf(xv, w[j], acc[j]);
    }
    int n = node0 + lane;
    if (n >= N) return;
    const int os = g * OG;
#pragma unroll
    for (int j = 0; j < OG; ++j) {
        int o = os + j;
        if (o < OUT) {
            float v = acc[j];
            if (BIAS) v += bgp[g * OGP + j];
            if (RELU) v = fmaxf(v, 0.0f);
            stf<BF16_OUT>(Yv, (ll)n * ystride + o, v);
        }
    }
}

// ---------------- pooled init ----------------
__global__ void k_pool_init(unsigned* pooled) {
    int t = threadIdx.x;
    if (t < 64 * 3) pooled[t] = ENC_NEG_INF;
}

// ---------------- head: z = relu(Y3 + b3) @ Wo + bo; hierarchical segment-max ----------------
__global__ void k_head(const float* __restrict__ Y3, int ystride, const float* __restrict__ wf,
                       const int* __restrict__ batch, unsigned* __restrict__ pooled,
                       const int* __restrict__ flags, int N) {
    __shared__ float Ws[50 * 3];
    __shared__ float bs[50];
    __shared__ float bos[3];
    __shared__ unsigned lmax[192];
    int wi = flags[1];
    for (int i = threadIdx.x; i < 150; i += blockDim.x) Ws[i] = wf[OHW + i];
    for (int i = threadIdx.x; i < 50; i += blockDim.x) bs[i] = wf[OHB3 + i];
    if (threadIdx.x < 3) bos[threadIdx.x] = wf[OHBO + threadIdx.x];
    for (int i = threadIdx.x; i < 192; i += blockDim.x) lmax[i] = ENC_NEG_INF;
    __syncthreads();
    int n = blockIdx.x * blockDim.x + threadIdx.x;
    int lane = threadIdx.x & 63;
    float z0 = 0.0f, z1 = 0.0f, z2 = 0.0f;
    int g = 0;
    if (n < N) {
        z0 = bos[0];
        z1 = bos[1];
        z2 = bos[2];
        const float* y = Y3 + (ll)n * ystride;
#pragma unroll
        for (int k = 0; k < 50; ++k) {
            float h = fmaxf(y[k] + bs[k], 0.0f);
            z0 = fmaf(h, Ws[k * 3 + 0], z0);
            z1 = fmaf(h, Ws[k * 3 + 1], z1);
            z2 = fmaf(h, Ws[k * 3 + 2], z2);
        }
        g = ldi(batch, n, wi);
    }
    int g0 = __shfl(g, 0);
    unsigned long long uni = __ballot(n < N && g == g0);
    if (uni == ~0ULL) {
#pragma unroll
        for (int off = 32; off > 0; off >>= 1) {
            z0 = fmaxf(z0, __shfl_xor(z0, off));
            z1 = fmaxf(z1, __shfl_xor(z1, off));
            z2 = fmaxf(z2, __shfl_xor(z2, off));
        }
        if (lane == 0) {
            atomicMax(&lmax[g0 * 3 + 0], fenc(z0));
            atomicMax(&lmax[g0 * 3 + 1], fenc(z1));
            atomicMax(&lmax[g0 * 3 + 2], fenc(z2));
        }
    } else if (n < N) {
        atomicMax(&lmax[g * 3 + 0], fenc(z0));
        atomicMax(&lmax[g * 3 + 1], fenc(z1));
        atomicMax(&lmax[g * 3 + 2], fenc(z2));
    }
    __syncthreads();
    for (int i = threadIdx.x; i < 192; i += blockDim.x) {
        unsigned v = lmax[i];
        if (v != ENC_NEG_INF) atomicMax(&pooled[i], v);
    }
}

// ---------------- softmax over [64,3] ----------------
__global__ void k_softmax(const unsigned* __restrict__ pooled, void* __restrict__ out,
                          const int* __restrict__ flags) {
    int g = threadIdx.x;
    if (g >= 64) return;
    int bf = flags[0];
    float a = fdec(pooled[g * 3 + 0]);
    float b = fdec(pooled[g * 3 + 1]);
    float c = fdec(pooled[g * 3 + 2]);
    float m = fmaxf(a, fmaxf(b, c));
    float ea = __expf(a - m), eb = __expf(b - m), ec = __expf(c - m);
    float s = 1.0f / (ea + eb + ec);
    if (bf) {
        __hip_bfloat16* o = (__hip_bfloat16*)out;
        o[g * 3 + 0] = __float2bfloat16(ea * s);
        o[g * 3 + 1] = __float2bfloat16(eb * s);
        o[g * 3 + 2] = __float2bfloat16(ec * s);
    } else {
        float* o = (float*)out;
        o[g * 3 + 0] = ea * s;
        o[g * 3 + 1] = eb * s;
        o[g * 3 + 2] = ec * s;
    }
}

extern "C" void kernel_launch(void* const* d_in, const int* in_sizes, int n_in,
                              void* d_out, int out_size, void* d_ws, size_t ws_size,
                              hipStream_t stream) {
    const void* x = d_in[0];
    const int* ei = (const int*)d_in[1];
    const int* batch = (const int*)d_in[2];

    const int N = in_sizes[0] / 36;
    const int E = in_sizes[1] / 2;

    // ---- workspace carve ----
    char* ws = (char*)d_ws;
    size_t off = 0;
    auto carve = [&](size_t bytes) {
        char* p = ws + off;
        off = (off + bytes + 255) & ~(size_t)255;
        return p;
    };
    int* flags = (int*)carve(16);
    float* wf = (float*)carve((size_t)N_WF2 * 4);  // grouped f32 weight pool
    float* dinv = (float*)carve((size_t)N * 4);
    int* cnt = (int*)carve((size_t)N * 4);
    int* rowptr = (int*)carve((size_t)(N + 1) * 4);
    int2* ep = (int2*)carve((size_t)E * 8);  // interleaved (src, weight)
    unsigned* pooled = (unsigned*)carve(768);
    const int NB = DIV_UP(N + 1, 256);
    int* bsum = (int*)carve((size_t)NB * 4);
    char* R1 = carve((size_t)N * 304);  // A1 f32 s76 | A2 f32 s76 | T3 bf16 s76
    char* R2 = carve((size_t)N * 304);  // H1 bf16 s76 | H2 bf16 s152 | Y3 f32 s76
    (void)carve(65536);                 // pad: unguarded GEMM staging may overread past R2

    const int B = 256;
    const int GB = DIV_UP(N, 64);  // GEMM blocks along nodes

    // 0. dtype detection + weight conversion/regrouping
    k_detect<<<1, 256, 0, stream>>>((const unsigned*)x, (const unsigned*)ei, flags);
    k_cvt<<<DIV_UP(N_WF2, B), B, 0, stream>>>(d_in[3], d_in[4], d_in[5], d_in[6], d_in[7], d_in[8],
                                              d_in[9], d_in[10], wf, flags);

    // 1. CSR build
    k_zero<<<DIV_UP(N, B), B, 0, stream>>>(cnt, N);
    k_hist<<<DIV_UP(E, B), B, 0, stream>>>(ei, cnt, flags, E);
    k_scan1<<<NB, 256, 0, stream>>>(cnt, bsum, dinv, N);
    k_scan2<<<1, 256, 0, stream>>>(bsum, NB);
    k_scan3<<<NB, 256, 0, stream>>>(cnt, bsum, rowptr, N);
    k_zero<<<DIV_UP(N, B), B, 0, stream>>>(cnt, N);
    k_fill<<<DIV_UP(E, B), B, 0, stream>>>(ei, rowptr, cnt, ep, dinv, flags, E);

    // 2. layer 1: aggregate x (36) -> A1 f32, GEMM 36->75 relu -> H1 bf16
    k_agg<2><<<DIV_UP(N, 4), B, 0, stream>>>(x, 36, (float*)R1, 76, 36, rowptr, ep, dinv, flags, N);
    k_gemm<36, 75, 10, 12, true, true, false, true>
        <<<dim3(GB, 2), B, 0, stream>>>(R1, 76, R2, 76, wf + G1W, wf + G1B, N);

    // 3. layer 2: aggregate H1 bf16 (75) -> A2 f32, GEMM 75->150 relu -> H2 bf16
    k_agg<1><<<DIV_UP(N, 4), B, 0, stream>>>(R2, 76, (float*)R1, 76, 75, rowptr, ep, dinv, flags,
                                             N);
    k_gemm<75, 150, 10, 12, true, true, false, true>
        <<<dim3(GB, 4), B, 0, stream>>>(R1, 76, R2, 152, wf + G2W, wf + G2B, N);

    // 4. layer 3: GEMM 150->50 (no act) -> T3 bf16, aggregate bf16 (50) -> Y3 f32
    k_gemm<150, 50, 13, 16, false, false, true, true>
        <<<dim3(GB, 1), B, 0, stream>>>(R2, 152, R1, 76, wf + G3W, wf + G3B, N);
    k_agg<1><<<DIV_UP(N, 4), B, 0, stream>>>(R1, 76, (float*)R2, 76, 50, rowptr, ep, dinv, flags,
                                             N);

    // 5. head + pooling + softmax
    k_pool_init<<<1, 192, 0, stream>>>(pooled);
    k_head<<<DIV_UP(N, B), B, 0, stream>>>((const float*)R2, 76, wf, batch, pooled, flags, N);
    k_softmax<<<1, 64, 0, stream>>>(pooled, d_out, flags);
}

// Round 11
// 281.577 us; speedup vs baseline: 1.3834x; 1.3834x over previous
//
#include <hip/hip_runtime.h>
#include <hip/hip_bf16.h>

#define DIV_UP(a, b) (((a) + (b) - 1) / (b))
typedef long long ll;
typedef __attribute__((ext_vector_type(8))) short short8;
typedef __attribute__((ext_vector_type(4))) float f32x4;

// ---------- runtime-dtype helpers ----------
__device__ __forceinline__ float ldf(const void* p, ll i, int bf) {
    return bf ? __bfloat162float(((const __hip_bfloat16*)p)[i]) : ((const float*)p)[i];
}
__device__ __forceinline__ int ldi(const int* p, ll i, int w) {
    return w ? p[2 * i] : p[i];
}
// MODE: 1 = bf16 (compile-time), 2 = external (runtime bf flag)
template <int MODE>
__device__ __forceinline__ float ldm(const void* p, ll i, int bf) {
    if (MODE == 1) return __bfloat162float(((const __hip_bfloat16*)p)[i]);
    return ldf(p, i, bf);
}

// ---- ordered-uint encoding for float atomicMax ----
__device__ __forceinline__ unsigned fenc(float f) {
    unsigned u = __float_as_uint(f);
    return (u & 0x80000000u) ? ~u : (u | 0x80000000u);
}
__device__ __forceinline__ float fdec(unsigned u) {
    unsigned v = (u & 0x80000000u) ? (u & 0x7FFFFFFFu) : ~u;
    return __uint_as_float(v);
}
#define ENC_NEG_INF 0x007FFFFFu

// ---- f32 misc pool offsets ----
#define MB1 0    // b1: 75
#define MB2 80   // b2: 150
#define MHW 240  // Wo: 150
#define MB3 390  // b3: 50
#define MBO 440  // bo: 3
#define N_MISC 444
// ---- Wpack (bf16, B-fragment layout) region bases, in bf16 elements ----
#define P1 0      // L1: CT=5, KC=2 -> 5120
#define P2 5120   // L2: CT=10, KC=3 -> 15360
#define P3 20480  // L3: CT=4, KC=5 -> 10240
#define N_PACK 30720

// ---------------- dtype detection ----------------
__global__ void k_detect(const unsigned* __restrict__ xb, const unsigned* __restrict__ eb,
                         int* __restrict__ flags) {
    __shared__ int sv[2];
    int t = threadIdx.x;
    if (t < 2) sv[t] = 0;
    __syncthreads();
    unsigned e = (xb[t] >> 7) & 0xFFu;
    int vote = (e >= 115u && e <= 133u) ? 1 : 0;
    int zero = (eb[2 * t + 1] == 0u) ? 1 : 0;
    atomicAdd(&sv[0], vote);
    atomicAdd(&sv[1], zero);
    __syncthreads();
    if (t == 0) {
        flags[0] = (sv[0] > 128) ? 1 : 0;
        flags[1] = (sv[1] > 200) ? 1 : 0;
    }
}

// ---------------- misc params -> f32 pool ----------------
__global__ void k_cvt_misc(const void* __restrict__ b1, const void* __restrict__ b2,
                           const void* __restrict__ Wo, const void* __restrict__ b3,
                           const void* __restrict__ bo, float* __restrict__ wfm,
                           const int* __restrict__ flags) {
    int t = blockIdx.x * blockDim.x + threadIdx.x;
    if (t >= N_MISC) return;
    int bf = flags[0];
    float v = 0.0f;
    if (t < 75)
        v = ldf(b1, t, bf);
    else if (t >= MB2 && t < MB2 + 150)
        v = ldf(b2, t - MB2, bf);
    else if (t >= MHW && t < MHW + 150)
        v = ldf(Wo, t - MHW, bf);
    else if (t >= MB3 && t < MB3 + 50)
        v = ldf(b3, t - MB3, bf);
    else if (t >= MBO && t < MBO + 3)
        v = ldf(bo, t - MBO, bf);
    wfm[t] = v;
}

// ---------------- pack W1/W2/W3 into MFMA B-fragment layout (bf16, zero-padded) -------------
// Layout: element index i within region: j=i&7 (k sub), lane=(i>>3)&63, tile=i>>9,
// kc=tile%KC, ct=tile/KC; k=kc*32+(lane>>4)*8+j; col=ct*16+(lane&15).
// A wave's B-frag load is then Wp[(ct*KC+kc)*64+lane] -> consecutive 16B per lane, coalesced.
__global__ void k_cvt_pack(const void* __restrict__ W1, const void* __restrict__ W2,
                           const void* __restrict__ W3, __hip_bfloat16* __restrict__ wp,
                           const int* __restrict__ flags) {
    int t = blockIdx.x * blockDim.x + threadIdx.x;
    if (t >= N_PACK) return;
    int bf = flags[0];
    const void* W;
    int i, K, OUT, KC;
    if (t < P2) {
        W = W1;
        i = t;
        K = 36;
        OUT = 75;
        KC = 2;
    } else if (t < P3) {
        W = W2;
        i = t - P2;
        K = 75;
        OUT = 150;
        KC = 3;
    } else {
        W = W3;
        i = t - P3;
        K = 150;
        OUT = 50;
        KC = 5;
    }
    int j = i & 7;
    int lane = (i >> 3) & 63;
    int tile = i >> 9;
    int kc = tile % KC;
    int ct = tile / KC;
    int k = kc * 32 + ((lane >> 4) << 3) + j;
    int col = ct * 16 + (lane & 15);
    float v = (k < K && col < OUT) ? ldf(W, (ll)k * OUT + col, bf) : 0.0f;
    wp[t] = __float2bfloat16(v);
}

// ---------------- CSR build ----------------
__global__ void k_zero(int* p, int n) {
    int t = blockIdx.x * blockDim.x + threadIdx.x;
    if (t < n) p[t] = 0;
}
__global__ void k_hist(const int* __restrict__ ei, int* __restrict__ cnt,
                       const int* __restrict__ flags, int E) {
    int t = blockIdx.x * blockDim.x + threadIdx.x;
    if (t >= E) return;
    atomicAdd(&cnt[ldi(ei, (ll)E + t, flags[1])], 1);
}
__global__ void k_scan1(const int* __restrict__ cnt, int* __restrict__ bsum,
                        float* __restrict__ dinv, int N) {
    __shared__ int s[256];
    int t = threadIdx.x;
    int idx = blockIdx.x * 256 + t;
    int v = (idx < N) ? cnt[idx] : 0;
    if (idx < N) dinv[idx] = rsqrtf((float)v + 1.0f);  // +1 self-loop
    s[t] = v;
    __syncthreads();
#pragma unroll
    for (int off = 128; off > 0; off >>= 1) {
        if (t < off) s[t] += s[t + off];
        __syncthreads();
    }
    if (t == 0) bsum[blockIdx.x] = s[0];
}
__global__ void k_scan2(int* __restrict__ bsum, int nb) {
    __shared__ int s[256];
    int t = threadIdx.x;
    int run = 0;
    for (int base = 0; base < nb; base += 256) {
        int i = base + t;
        int v = (i < nb) ? bsum[i] : 0;
        s[t] = v;
        __syncthreads();
        for (int off = 1; off < 256; off <<= 1) {
            int o = (t >= off) ? s[t - off] : 0;
            __syncthreads();
            s[t] += o;
            __syncthreads();
        }
        if (i < nb) bsum[i] = run + s[t] - v;
        run += s[255];
        __syncthreads();
    }
}
__global__ void k_scan3(const int* __restrict__ cnt, const int* __restrict__ bsum,
                        int* __restrict__ rowptr, int N) {
    __shared__ int s[256];
    int t = threadIdx.x;
    int idx = blockIdx.x * 256 + t;
    int v = (idx < N) ? cnt[idx] : 0;
    s[t] = v;
    __syncthreads();
    for (int off = 1; off < 256; off <<= 1) {
        int o = (t >= off) ? s[t - off] : 0;
        __syncthreads();
        s[t] += o;
        __syncthreads();
    }
    if (idx <= N) rowptr[idx] = bsum[blockIdx.x] + s[t] - v;
}
__global__ void k_fill(const int* __restrict__ ei, const int* __restrict__ rowptr,
                       int* __restrict__ cursor, int2* __restrict__ ep,
                       const float* __restrict__ dinv, const int* __restrict__ flags, int E) {
    int t = blockIdx.x * blockDim.x + threadIdx.x;
    if (t >= E) return;
    int wi = flags[1];
    int s = ldi(ei, t, wi);
    int d = ldi(ei, (ll)E + t, wi);
    int pos = rowptr[d] + atomicAdd(&cursor[d], 1);
    int2 v;
    v.x = s;
    v.y = __float_as_int(dinv[s] * dinv[d]);
    ep[pos] = v;
}

// ---------------- CSR aggregation: Y[n] = dinv[n]^2*X[n] + sum_e w_e*X[src_e] ----------------
// wave per node; C <= 128; MODE = input dtype, OD = output (0 f32 / 1 bf16)
template <int MODE, int OD>
__global__ void k_agg(const void* __restrict__ X, int xstride, void* __restrict__ Yv, int ystride,
                      int C, const int* __restrict__ rowptr, const int2* __restrict__ ep,
                      const float* __restrict__ dinv, const int* __restrict__ flags, int N) {
    int n = blockIdx.x * 4 + (threadIdx.x >> 6);
    if (n >= N) return;
    int lane = threadIdx.x & 63;
    int bf = (MODE == 2) ? flags[0] : 0;
    float di = dinv[n];
    float w0 = di * di;
    int c1 = lane + 64;
    bool has0 = lane < C, has1 = c1 < C;
    float a0 = has0 ? w0 * ldm<MODE>(X, (ll)n * xstride + lane, bf) : 0.0f;
    float a1 = has1 ? w0 * ldm<MODE>(X, (ll)n * xstride + c1, bf) : 0.0f;
    int j = rowptr[n];
    int je = rowptr[n + 1];
    for (; j + 3 < je; j += 4) {
        int2 v0 = ep[j];
        int2 v1 = ep[j + 1];
        int2 v2 = ep[j + 2];
        int2 v3 = ep[j + 3];
        float wa = __int_as_float(v0.y), wb = __int_as_float(v1.y);
        float wc = __int_as_float(v2.y), wd = __int_as_float(v3.y);
        if (has0) {
            a0 = fmaf(wa, ldm<MODE>(X, (ll)v0.x * xstride + lane, bf), a0);
            a0 = fmaf(wb, ldm<MODE>(X, (ll)v1.x * xstride + lane, bf), a0);
            a0 = fmaf(wc, ldm<MODE>(X, (ll)v2.x * xstride + lane, bf), a0);
            a0 = fmaf(wd, ldm<MODE>(X, (ll)v3.x * xstride + lane, bf), a0);
        }
        if (has1) {
            a1 = fmaf(wa, ldm<MODE>(X, (ll)v0.x * xstride + c1, bf), a1);
            a1 = fmaf(wb, ldm<MODE>(X, (ll)v1.x * xstride + c1, bf), a1);
            a1 = fmaf(wc, ldm<MODE>(X, (ll)v2.x * xstride + c1, bf), a1);
            a1 = fmaf(wd, ldm<MODE>(X, (ll)v3.x * xstride + c1, bf), a1);
        }
    }
    for (; j < je; ++j) {
        int2 v0 = ep[j];
        float wa = __int_as_float(v0.y);
        if (has0) a0 = fmaf(wa, ldm<MODE>(X, (ll)v0.x * xstride + lane, bf), a0);
        if (has1) a1 = fmaf(wa, ldm<MODE>(X, (ll)v0.x * xstride + c1, bf), a1);
    }
    if (has0) {
        if (OD)
            ((__hip_bfloat16*)Yv)[(ll)n * ystride + lane] = __float2bfloat16(a0);
        else
            ((float*)Yv)[(ll)n * ystride + lane] = a0;
    }
    if (has1) {
        if (OD)
            ((__hip_bfloat16*)Yv)[(ll)n * ystride + c1] = __float2bfloat16(a1);
        else
            ((float*)Yv)[(ll)n * ystride + c1] = a1;
    }
}

// ---------------- MFMA GEMM: Y = act(X @ W + b), X bf16 row-major (stride >= KC*32) -------
// wave = 16 nodes x OUT cols via mfma_f32_16x16x32_bf16. No LDS, no in-loop SMEM.
// A-frag: lane holds A[m=lane&15][k=kc*32+(lane>>4)*8+j] = one 16B load from node row.
// B-frag: pre-packed (k_cvt_pack) so lane's load is Wp[(ct*KC+kc)*64+lane] - coalesced.
// D: col=lane&15, row=(lane>>4)*4+reg (verified m89/m91). Writeback guarded; A-row
// overreads (node>=N, k>=K) hit finite poison multiplied by zero-padded B -> 0.
// #pragma unroll 1 on kc bounds live B-frags (R6 spill lesson).
template <int K, int KC, int OUT, int CT, bool RELU, bool BIAS>
__global__ __launch_bounds__(256) void k_gemm(const __hip_bfloat16* __restrict__ X, int xs,
                                              __hip_bfloat16* __restrict__ Y, int ys,
                                              const short8* __restrict__ Wp,
                                              const float* __restrict__ bias, int N) {
    const int lane = threadIdx.x & 63;
    const int wid = threadIdx.x >> 6;
    const int m0 = blockIdx.x * 64 + wid * 16;
    const int mrow = lane & 15;
    const int koct = lane >> 4;
    const __hip_bfloat16* xrow = X + (ll)(m0 + mrow) * xs + koct * 8;
    f32x4 acc[CT];
#pragma unroll
    for (int ct = 0; ct < CT; ++ct)
#pragma unroll
        for (int r = 0; r < 4; ++r) acc[ct][r] = 0.0f;
    float bv[CT];
#pragma unroll
    for (int ct = 0; ct < CT; ++ct) {
        int col = ct * 16 + mrow;
        bv[ct] = (BIAS && col < OUT) ? bias[col] : 0.0f;
    }
#pragma unroll 1
    for (int kc = 0; kc < KC; ++kc) {
        short8 a = *(const short8*)(xrow + kc * 32);
#pragma unroll
        for (int ct = 0; ct < CT; ++ct) {
            short8 b = Wp[(ct * KC + kc) * 64 + lane];
            acc[ct] = __builtin_amdgcn_mfma_f32_16x16x32_bf16(a, b, acc[ct], 0, 0, 0);
        }
    }
#pragma unroll
    for (int ct = 0; ct < CT; ++ct) {
        int col = ct * 16 + mrow;
        if (col >= OUT) continue;
#pragma unroll
        for (int r = 0; r < 4; ++r) {
            int node = m0 + koct * 4 + r;
            if (node >= N) continue;
            float v = acc[ct][r] + bv[ct];
            if (RELU) v = fmaxf(v, 0.0f);
            Y[(ll)node * ys + col] = __float2bfloat16(v);
        }
    }
}

// ---------------- pooled init ----------------
__global__ void k_pool_init(unsigned* pooled) {
    int t = threadIdx.x;
    if (t < 64 * 3) pooled[t] = ENC_NEG_INF;
}

// ---------------- head: z = relu(Y3 + b3) @ Wo + bo; hierarchical segment-max ----------------
__global__ void k_head(const float* __restrict__ Y3, int ystride, const float* __restrict__ wfm,
                       const int* __restrict__ batch, unsigned* __restrict__ pooled,
                       const int* __restrict__ flags, int N) {
    __shared__ float Ws[50 * 3];
    __shared__ float bs[50];
    __shared__ float bos[3];
    __shared__ unsigned lmax[192];
    int wi = flags[1];
    for (int i = threadIdx.x; i < 150; i += blockDim.x) Ws[i] = wfm[MHW + i];
    for (int i = threadIdx.x; i < 50; i += blockDim.x) bs[i] = wfm[MB3 + i];
    if (threadIdx.x < 3) bos[threadIdx.x] = wfm[MBO + threadIdx.x];
    for (int i = threadIdx.x; i < 192; i += blockDim.x) lmax[i] = ENC_NEG_INF;
    __syncthreads();
    int n = blockIdx.x * blockDim.x + threadIdx.x;
    int lane = threadIdx.x & 63;
    float z0 = 0.0f, z1 = 0.0f, z2 = 0.0f;
    int g = 0;
    if (n < N) {
        z0 = bos[0];
        z1 = bos[1];
        z2 = bos[2];
        const float* y = Y3 + (ll)n * ystride;
#pragma unroll
        for (int k = 0; k < 50; ++k) {
            float h = fmaxf(y[k] + bs[k], 0.0f);
            z0 = fmaf(h, Ws[k * 3 + 0], z0);
            z1 = fmaf(h, Ws[k * 3 + 1], z1);
            z2 = fmaf(h, Ws[k * 3 + 2], z2);
        }
        g = ldi(batch, n, wi);
    }
    int g0 = __shfl(g, 0);
    unsigned long long uni = __ballot(n < N && g == g0);
    if (uni == ~0ULL) {
#pragma unroll
        for (int off = 32; off > 0; off >>= 1) {
            z0 = fmaxf(z0, __shfl_xor(z0, off));
            z1 = fmaxf(z1, __shfl_xor(z1, off));
            z2 = fmaxf(z2, __shfl_xor(z2, off));
        }
        if (lane == 0) {
            atomicMax(&lmax[g0 * 3 + 0], fenc(z0));
            atomicMax(&lmax[g0 * 3 + 1], fenc(z1));
            atomicMax(&lmax[g0 * 3 + 2], fenc(z2));
        }
    } else if (n < N) {
        atomicMax(&lmax[g * 3 + 0], fenc(z0));
        atomicMax(&lmax[g * 3 + 1], fenc(z1));
        atomicMax(&lmax[g * 3 + 2], fenc(z2));
    }
    __syncthreads();
    for (int i = threadIdx.x; i < 192; i += blockDim.x) {
        unsigned v = lmax[i];
        if (v != ENC_NEG_INF) atomicMax(&pooled[i], v);
    }
}

// ---------------- softmax over [64,3] ----------------
__global__ void k_softmax(const unsigned* __restrict__ pooled, void* __restrict__ out,
                          const int* __restrict__ flags) {
    int g = threadIdx.x;
    if (g >= 64) return;
    int bf = flags[0];
    float a = fdec(pooled[g * 3 + 0]);
    float b = fdec(pooled[g * 3 + 1]);
    float c = fdec(pooled[g * 3 + 2]);
    float m = fmaxf(a, fmaxf(b, c));
    float ea = __expf(a - m), eb = __expf(b - m), ec = __expf(c - m);
    float s = 1.0f / (ea + eb + ec);
    if (bf) {
        __hip_bfloat16* o = (__hip_bfloat16*)out;
        o[g * 3 + 0] = __float2bfloat16(ea * s);
        o[g * 3 + 1] = __float2bfloat16(eb * s);
        o[g * 3 + 2] = __float2bfloat16(ec * s);
    } else {
        float* o = (float*)out;
        o[g * 3 + 0] = ea * s;
        o[g * 3 + 1] = eb * s;
        o[g * 3 + 2] = ec * s;
    }
}

extern "C" void kernel_launch(void* const* d_in, const int* in_sizes, int n_in,
                              void* d_out, int out_size, void* d_ws, size_t ws_size,
                              hipStream_t stream) {
    const void* x = d_in[0];
    const int* ei = (const int*)d_in[1];
    const int* batch = (const int*)d_in[2];

    const int N = in_sizes[0] / 36;
    const int E = in_sizes[1] / 2;

    // ---- workspace carve ----
    char* ws = (char*)d_ws;
    size_t off = 0;
    auto carve = [&](size_t bytes) {
        char* p = ws + off;
        off = (off + bytes + 255) & ~(size_t)255;
        return p;
    };
    int* flags = (int*)carve(16);
    float* wfm = (float*)carve((size_t)N_MISC * 4);
    __hip_bfloat16* wpack = (__hip_bfloat16*)carve((size_t)N_PACK * 2);
    float* dinv = (float*)carve((size_t)N * 4);
    int* cnt = (int*)carve((size_t)N * 4);
    int* rowptr = (int*)carve((size_t)(N + 1) * 4);
    int2* ep = (int2*)carve((size_t)E * 8);
    unsigned* pooled = (unsigned*)carve(768);
    const int NB = DIV_UP(N + 1, 256);
    int* bsum = (int*)carve((size_t)NB * 4);
    // R1: A1 bf16 s64 (128B) | A2 bf16 s96 (192B) | T3 bf16 s64 (128B)
    char* R1 = carve((size_t)N * 192);
    // R2: H1 bf16 s80 (160B) | H2 bf16 s160 (320B) | Y3 f32 s50 (200B)
    char* R2 = carve((size_t)N * 320);
    (void)carve(65536);  // pad: unguarded GEMM A-row overreads stay in workspace

    const int B = 256;
    const int GB = DIV_UP(N, 64);

    // 0. dtype detection + weight conversion/packing
    k_detect<<<1, 256, 0, stream>>>((const unsigned*)x, (const unsigned*)ei, flags);
    k_cvt_misc<<<2, 256, 0, stream>>>(d_in[4], d_in[6], d_in[9], d_in[8], d_in[10], wfm, flags);
    k_cvt_pack<<<DIV_UP(N_PACK, B), B, 0, stream>>>(d_in[3], d_in[5], d_in[7], wpack, flags);

    // 1. CSR build
    k_zero<<<DIV_UP(N, B), B, 0, stream>>>(cnt, N);
    k_hist<<<DIV_UP(E, B), B, 0, stream>>>(ei, cnt, flags, E);
    k_scan1<<<NB, 256, 0, stream>>>(cnt, bsum, dinv, N);
    k_scan2<<<1, 256, 0, stream>>>(bsum, NB);
    k_scan3<<<NB, 256, 0, stream>>>(cnt, bsum, rowptr, N);
    k_zero<<<DIV_UP(N, B), B, 0, stream>>>(cnt, N);
    k_fill<<<DIV_UP(E, B), B, 0, stream>>>(ei, rowptr, cnt, ep, dinv, flags, E);

    // 2. layer 1: agg x (36) -> A1 bf16 s64; MFMA GEMM 36->75 relu -> H1 bf16 s80
    k_agg<2, 1><<<DIV_UP(N, 4), B, 0, stream>>>(x, 36, R1, 64, 36, rowptr, ep, dinv, flags, N);
    k_gemm<36, 2, 75, 5, true, true><<<GB, B, 0, stream>>>(
        (const __hip_bfloat16*)R1, 64, (__hip_bfloat16*)R2, 80, (const short8*)(wpack + P1),
        wfm + MB1, N);

    // 3. layer 2: agg H1 (75) -> A2 bf16 s96; MFMA GEMM 75->150 relu -> H2 bf16 s160
    k_agg<1, 1><<<DIV_UP(N, 4), B, 0, stream>>>(R2, 80, R1, 96, 75, rowptr, ep, dinv, flags, N);
    k_gemm<75, 3, 150, 10, true, true><<<GB, B, 0, stream>>>(
        (const __hip_bfloat16*)R1, 96, (__hip_bfloat16*)R2, 160, (const short8*)(wpack + P2),
        wfm + MB2, N);

    // 4. layer 3: MFMA GEMM 150->50 -> T3 bf16 s64; agg T3 (50) -> Y3 f32 s50
    k_gemm<150, 5, 50, 4, false, false><<<GB, B, 0, stream>>>(
        (const __hip_bfloat16*)R2, 160, (__hip_bfloat16*)R1, 64, (const short8*)(wpack + P3), wfm,
        N);
    k_agg<1, 0><<<DIV_UP(N, 4), B, 0, stream>>>(R1, 64, R2, 50, 50, rowptr, ep, dinv, flags, N);

    // 5. head + pooling + softmax
    k_pool_init<<<1, 192, 0, stream>>>(pooled);
    k_head<<<DIV_UP(N, B), B, 0, stream>>>((const float*)R2, 50, wfm, batch, pooled, flags, N);
    k_softmax<<<1, 64, 0, stream>>>(pooled, d_out, flags);
}

// Round 12
// 254.784 us; speedup vs baseline: 1.5289x; 1.1052x over previous
//
#include <hip/hip_runtime.h>
#include <hip/hip_bf16.h>

#define DIV_UP(a, b) (((a) + (b) - 1) / (b))
typedef long long ll;
typedef __attribute__((ext_vector_type(8))) short short8;
typedef __attribute__((ext_vector_type(4))) float f32x4;

// ---------- runtime-dtype helpers ----------
__device__ __forceinline__ float ldf(const void* p, ll i, int bf) {
    return bf ? __bfloat162float(((const __hip_bfloat16*)p)[i]) : ((const float*)p)[i];
}
__device__ __forceinline__ int ldi(const int* p, ll i, int w) {
    return w ? p[2 * i] : p[i];
}
// MODE: 1 = bf16 (compile-time), 2 = external (runtime bf flag)
template <int MODE>
__device__ __forceinline__ float ldm(const void* p, ll i, int bf) {
    if (MODE == 1) return __bfloat162float(((const __hip_bfloat16*)p)[i]);
    return ldf(p, i, bf);
}
// decode packed bf16 pair (little-endian: low 16 bits = even col)
__device__ __forceinline__ void bf16pair(unsigned u, float& f0, float& f1) {
    f0 = __uint_as_float(u << 16);
    f1 = __uint_as_float(u & 0xFFFF0000u);
}

// ---- ordered-uint encoding for float atomicMax ----
__device__ __forceinline__ unsigned fenc(float f) {
    unsigned u = __float_as_uint(f);
    return (u & 0x80000000u) ? ~u : (u | 0x80000000u);
}
__device__ __forceinline__ float fdec(unsigned u) {
    unsigned v = (u & 0x80000000u) ? (u & 0x7FFFFFFFu) : ~u;
    return __uint_as_float(v);
}
#define ENC_NEG_INF 0x007FFFFFu

// ---- f32 misc pool offsets ----
#define MB1 0    // b1: 75
#define MB2 80   // b2: 150
#define MHW 240  // Wo: 150
#define MB3 390  // b3: 50
#define MBO 440  // bo: 3
#define N_MISC 444
// ---- Wpack (bf16, B-fragment layout) region bases, in bf16 elements ----
#define P1 0      // L1: CT=5, KC=2 -> 5120
#define P2 5120   // L2: CT=10, KC=3 -> 15360
#define P3 20480  // L3: CT=4, KC=5 -> 10240
#define N_PACK 30720

// ---------------- dtype detection + cnt zero (fused, grid-wide) ----------------
__global__ void k_detect(const unsigned* __restrict__ xb, const unsigned* __restrict__ eb,
                         int* __restrict__ flags, int* __restrict__ cnt, int N) {
    int idx = blockIdx.x * 256 + threadIdx.x;
    if (idx < N) cnt[idx] = 0;
    if (blockIdx.x != 0) return;
    __shared__ int sv[2];
    int t = threadIdx.x;
    if (t < 2) sv[t] = 0;
    __syncthreads();
    unsigned e = (xb[t] >> 7) & 0xFFu;
    int vote = (e >= 115u && e <= 133u) ? 1 : 0;
    int zero = (eb[2 * t + 1] == 0u) ? 1 : 0;
    atomicAdd(&sv[0], vote);
    atomicAdd(&sv[1], zero);
    __syncthreads();
    if (t == 0) {
        flags[0] = (sv[0] > 128) ? 1 : 0;
        flags[1] = (sv[1] > 200) ? 1 : 0;
    }
}

// ---------------- weight conversion: MFMA B-fragment pack + misc f32 pool (fused) ---------
// Pack layout: within region, i: j=i&7 (k sub), lane=(i>>3)&63, tile=i>>9, kc=tile%KC,
// ct=tile/KC; k=kc*32+(lane>>4)*8+j; col=ct*16+(lane&15). Wave B-load = Wp[(ct*KC+kc)*64+lane].
__global__ void k_cvt(const void* __restrict__ W1, const void* __restrict__ b1,
                      const void* __restrict__ W2, const void* __restrict__ b2,
                      const void* __restrict__ W3, const void* __restrict__ b3,
                      const void* __restrict__ Wo, const void* __restrict__ bo,
                      __hip_bfloat16* __restrict__ wp, float* __restrict__ wfm,
                      const int* __restrict__ flags) {
    int t = blockIdx.x * blockDim.x + threadIdx.x;
    int bf = flags[0];
    if (t < N_PACK) {
        const void* W;
        int i, K, OUT, KC;
        if (t < P2) {
            W = W1;
            i = t;
            K = 36;
            OUT = 75;
            KC = 2;
        } else if (t < P3) {
            W = W2;
            i = t - P2;
            K = 75;
            OUT = 150;
            KC = 3;
        } else {
            W = W3;
            i = t - P3;
            K = 150;
            OUT = 50;
            KC = 5;
        }
        int j = i & 7;
        int lane = (i >> 3) & 63;
        int tile = i >> 9;
        int kc = tile % KC;
        int ct = tile / KC;
        int k = kc * 32 + ((lane >> 4) << 3) + j;
        int col = ct * 16 + (lane & 15);
        float v = (k < K && col < OUT) ? ldf(W, (ll)k * OUT + col, bf) : 0.0f;
        wp[t] = __float2bfloat16(v);
    } else {
        int m = t - N_PACK;
        if (m >= N_MISC) return;
        float v = 0.0f;
        if (m < 75)
            v = ldf(b1, m, bf);
        else if (m >= MB2 && m < MB2 + 150)
            v = ldf(b2, m - MB2, bf);
        else if (m >= MHW && m < MHW + 150)
            v = ldf(Wo, m - MHW, bf);
        else if (m >= MB3 && m < MB3 + 50)
            v = ldf(b3, m - MB3, bf);
        else if (m >= MBO && m < MBO + 3)
            v = ldf(bo, m - MBO, bf);
        wfm[m] = v;
    }
}

// ---------------- CSR build ----------------
__global__ void k_hist(const int* __restrict__ ei, int* __restrict__ cnt,
                       const int* __restrict__ flags, int E) {
    int t = blockIdx.x * blockDim.x + threadIdx.x;
    if (t >= E) return;
    atomicAdd(&cnt[ldi(ei, (ll)E + t, flags[1])], 1);
}
__global__ void k_scan1(const int* __restrict__ cnt, int* __restrict__ bsum,
                        float* __restrict__ dinv, int N) {
    __shared__ int s[256];
    int t = threadIdx.x;
    int idx = blockIdx.x * 256 + t;
    int v = (idx < N) ? cnt[idx] : 0;
    if (idx < N) dinv[idx] = rsqrtf((float)v + 1.0f);  // +1 self-loop
    s[t] = v;
    __syncthreads();
#pragma unroll
    for (int off = 128; off > 0; off >>= 1) {
        if (t < off) s[t] += s[t + off];
        __syncthreads();
    }
    if (t == 0) bsum[blockIdx.x] = s[0];
}
// single-block scan of bsum; also inits pooled (fused - runs long before k_pool)
__global__ void k_scan2(int* __restrict__ bsum, int nb, unsigned* __restrict__ pooled) {
    __shared__ int s[256];
    int t = threadIdx.x;
    if (t < 192) pooled[t] = ENC_NEG_INF;
    int run = 0;
    for (int base = 0; base < nb; base += 256) {
        int i = base + t;
        int v = (i < nb) ? bsum[i] : 0;
        s[t] = v;
        __syncthreads();
        for (int off = 1; off < 256; off <<= 1) {
            int o = (t >= off) ? s[t - off] : 0;
            __syncthreads();
            s[t] += o;
            __syncthreads();
        }
        if (i < nb) bsum[i] = run + s[t] - v;
        run += s[255];
        __syncthreads();
    }
}
// per-block local scan + offset -> rowptr; re-zeroes cnt for use as k_fill cursor (fused)
__global__ void k_scan3(int* __restrict__ cnt, const int* __restrict__ bsum,
                        int* __restrict__ rowptr, int N) {
    __shared__ int s[256];
    int t = threadIdx.x;
    int idx = blockIdx.x * 256 + t;
    int v = (idx < N) ? cnt[idx] : 0;
    if (idx < N) cnt[idx] = 0;
    s[t] = v;
    __syncthreads();
    for (int off = 1; off < 256; off <<= 1) {
        int o = (t >= off) ? s[t - off] : 0;
        __syncthreads();
        s[t] += o;
        __syncthreads();
    }
    if (idx <= N) rowptr[idx] = bsum[blockIdx.x] + s[t] - v;
}
__global__ void k_fill(const int* __restrict__ ei, const int* __restrict__ rowptr,
                       int* __restrict__ cursor, int2* __restrict__ ep,
                       const float* __restrict__ dinv, const int* __restrict__ flags, int E) {
    int t = blockIdx.x * blockDim.x + threadIdx.x;
    if (t >= E) return;
    int wi = flags[1];
    int s = ldi(ei, t, wi);
    int d = ldi(ei, (ll)E + t, wi);
    int pos = rowptr[d] + atomicAdd(&cursor[d], 1);
    int2 v;
    v.x = s;
    v.y = __float_as_int(dinv[s] * dinv[d]);
    ep[pos] = v;
}

// ---------------- CSR aggregation (external input): Y[n] = dinv^2*X[n] + sum w_e*X[src] ----
// wave per node; C <= 64 here; output bf16
__global__ void k_agg(const void* __restrict__ X, int xstride, __hip_bfloat16* __restrict__ Y,
                      int ystride, int C, const int* __restrict__ rowptr,
                      const int2* __restrict__ ep, const float* __restrict__ dinv,
                      const int* __restrict__ flags, int N) {
    int n = blockIdx.x * 4 + (threadIdx.x >> 6);
    if (n >= N) return;
    int lane = threadIdx.x & 63;
    int bf = flags[0];
    float di = dinv[n];
    float w0 = di * di;
    if (lane >= C) return;
    float a0 = w0 * ldm<2>(X, (ll)n * xstride + lane, bf);
    int j = rowptr[n];
    int je = rowptr[n + 1];
    for (; j + 3 < je; j += 4) {
        int2 v0 = ep[j];
        int2 v1 = ep[j + 1];
        int2 v2 = ep[j + 2];
        int2 v3 = ep[j + 3];
        a0 = fmaf(__int_as_float(v0.y), ldm<2>(X, (ll)v0.x * xstride + lane, bf), a0);
        a0 = fmaf(__int_as_float(v1.y), ldm<2>(X, (ll)v1.x * xstride + lane, bf), a0);
        a0 = fmaf(__int_as_float(v2.y), ldm<2>(X, (ll)v2.x * xstride + lane, bf), a0);
        a0 = fmaf(__int_as_float(v3.y), ldm<2>(X, (ll)v3.x * xstride + lane, bf), a0);
    }
    for (; j < je; ++j) {
        int2 v0 = ep[j];
        a0 = fmaf(__int_as_float(v0.y), ldm<2>(X, (ll)v0.x * xstride + lane, bf), a0);
    }
    Y[(ll)n * ystride + lane] = __float2bfloat16(a0);
}

// ---------------- paired bf16 CSR aggregation: lane handles cols (2l, 2l+1) ----------------
// One 4B load per lane per gather. Pair store may include one pad col past C (odd C);
// safe: downstream MFMA B operand is zero-padded there.
__global__ void k_aggp(const __hip_bfloat16* __restrict__ X, int xs,
                       __hip_bfloat16* __restrict__ Y, int ys, int CP,
                       const int* __restrict__ rowptr, const int2* __restrict__ ep,
                       const float* __restrict__ dinv, int N) {
    int n = blockIdx.x * 4 + (threadIdx.x >> 6);
    if (n >= N) return;
    int lane = threadIdx.x & 63;
    if (lane >= CP) return;
    float di = dinv[n];
    float w0 = di * di;
    float a0, a1;
    {
        unsigned u = *(const unsigned*)(X + (ll)n * xs + 2 * lane);
        float f0, f1;
        bf16pair(u, f0, f1);
        a0 = w0 * f0;
        a1 = w0 * f1;
    }
    int j = rowptr[n];
    int je = rowptr[n + 1];
    for (; j + 3 < je; j += 4) {
        int2 v0 = ep[j];
        int2 v1 = ep[j + 1];
        int2 v2 = ep[j + 2];
        int2 v3 = ep[j + 3];
        unsigned u0 = *(const unsigned*)(X + (ll)v0.x * xs + 2 * lane);
        unsigned u1 = *(const unsigned*)(X + (ll)v1.x * xs + 2 * lane);
        unsigned u2 = *(const unsigned*)(X + (ll)v2.x * xs + 2 * lane);
        unsigned u3 = *(const unsigned*)(X + (ll)v3.x * xs + 2 * lane);
        float f0, f1;
        bf16pair(u0, f0, f1);
        float wa = __int_as_float(v0.y);
        a0 = fmaf(wa, f0, a0);
        a1 = fmaf(wa, f1, a1);
        bf16pair(u1, f0, f1);
        wa = __int_as_float(v1.y);
        a0 = fmaf(wa, f0, a0);
        a1 = fmaf(wa, f1, a1);
        bf16pair(u2, f0, f1);
        wa = __int_as_float(v2.y);
        a0 = fmaf(wa, f0, a0);
        a1 = fmaf(wa, f1, a1);
        bf16pair(u3, f0, f1);
        wa = __int_as_float(v3.y);
        a0 = fmaf(wa, f0, a0);
        a1 = fmaf(wa, f1, a1);
    }
    for (; j < je; ++j) {
        int2 v0 = ep[j];
        unsigned u = *(const unsigned*)(X + (ll)v0.x * xs + 2 * lane);
        float f0, f1;
        bf16pair(u, f0, f1);
        float wa = __int_as_float(v0.y);
        a0 = fmaf(wa, f0, a0);
        a1 = fmaf(wa, f1, a1);
    }
    __hip_bfloat162 h;
    h.x = __float2bfloat16(a0);
    h.y = __float2bfloat16(a1);
    *(__hip_bfloat162*)(Y + (ll)n * ys + 2 * lane) = h;
}

// ---------------- fused layer-3 aggregation + head: T3 -> z[n,3] (compact) ----------------
// wave per node, CP=25 pairs of T3 cols; per lane: h=relu(a+b3), partial z_c = h.Wo;
// wave shuffle-reduce sums -> lane0 writes zbuf[n*3..+2]. Replaces Y3 (10MB w + 10MB r)
// with 0.6MB zbuf. All lanes stay alive for the shuffle (inactive contribute 0).
__global__ void k_agg3h(const __hip_bfloat16* __restrict__ X, int xs, float* __restrict__ zb,
                        const int* __restrict__ rowptr, const int2* __restrict__ ep,
                        const float* __restrict__ dinv, const float* __restrict__ wfm, int N) {
    int n = blockIdx.x * 4 + (threadIdx.x >> 6);
    if (n >= N) return;
    int lane = threadIdx.x & 63;
    bool act = lane < 25;
    int c0 = 2 * lane;
    float w00 = 0, w01 = 0, w02 = 0, w10 = 0, w11 = 0, w12 = 0, bb0 = 0, bb1 = 0;
    if (act) {
        w00 = wfm[MHW + c0 * 3 + 0];
        w01 = wfm[MHW + c0 * 3 + 1];
        w02 = wfm[MHW + c0 * 3 + 2];
        w10 = wfm[MHW + c0 * 3 + 3];
        w11 = wfm[MHW + c0 * 3 + 4];
        w12 = wfm[MHW + c0 * 3 + 5];
        bb0 = wfm[MB3 + c0];
        bb1 = wfm[MB3 + c0 + 1];
    }
    float di = dinv[n];
    float w0 = di * di;
    float a0 = 0.0f, a1 = 0.0f;
    if (act) {
        unsigned u = *(const unsigned*)(X + (ll)n * xs + 2 * lane);
        float f0, f1;
        bf16pair(u, f0, f1);
        a0 = w0 * f0;
        a1 = w0 * f1;
    }
    int j = rowptr[n];
    int je = rowptr[n + 1];
    for (; j + 3 < je; j += 4) {
        int2 v0 = ep[j];
        int2 v1 = ep[j + 1];
        int2 v2 = ep[j + 2];
        int2 v3 = ep[j + 3];
        if (act) {
            unsigned u0 = *(const unsigned*)(X + (ll)v0.x * xs + 2 * lane);
            unsigned u1 = *(const unsigned*)(X + (ll)v1.x * xs + 2 * lane);
            unsigned u2 = *(const unsigned*)(X + (ll)v2.x * xs + 2 * lane);
            unsigned u3 = *(const unsigned*)(X + (ll)v3.x * xs + 2 * lane);
            float f0, f1;
            bf16pair(u0, f0, f1);
            float wa = __int_as_float(v0.y);
            a0 = fmaf(wa, f0, a0);
            a1 = fmaf(wa, f1, a1);
            bf16pair(u1, f0, f1);
            wa = __int_as_float(v1.y);
            a0 = fmaf(wa, f0, a0);
            a1 = fmaf(wa, f1, a1);
            bf16pair(u2, f0, f1);
            wa = __int_as_float(v2.y);
            a0 = fmaf(wa, f0, a0);
            a1 = fmaf(wa, f1, a1);
            bf16pair(u3, f0, f1);
            wa = __int_as_float(v3.y);
            a0 = fmaf(wa, f0, a0);
            a1 = fmaf(wa, f1, a1);
        }
    }
    for (; j < je; ++j) {
        int2 v0 = ep[j];
        if (act) {
            unsigned u = *(const unsigned*)(X + (ll)v0.x * xs + 2 * lane);
            float f0, f1;
            bf16pair(u, f0, f1);
            float wa = __int_as_float(v0.y);
            a0 = fmaf(wa, f0, a0);
            a1 = fmaf(wa, f1, a1);
        }
    }
    float h0 = act ? fmaxf(a0 + bb0, 0.0f) : 0.0f;
    float h1 = act ? fmaxf(a1 + bb1, 0.0f) : 0.0f;
    float z0 = h0 * w00 + h1 * w10;
    float z1 = h0 * w01 + h1 * w11;
    float z2 = h0 * w02 + h1 * w12;
#pragma unroll
    for (int off = 32; off > 0; off >>= 1) {
        z0 += __shfl_xor(z0, off);
        z1 += __shfl_xor(z1, off);
        z2 += __shfl_xor(z2, off);
    }
    if (lane == 0) {
        zb[(ll)n * 3 + 0] = z0 + wfm[MBO + 0];
        zb[(ll)n * 3 + 1] = z1 + wfm[MBO + 1];
        zb[(ll)n * 3 + 2] = z2 + wfm[MBO + 2];
    }
}

// ---------------- MFMA GEMM: Y = act(X @ W + b), X bf16 row-major (stride >= KC*32) -------
// wave = 16 nodes x OUT cols via mfma_f32_16x16x32_bf16. No LDS, no in-loop SMEM.
// A-frag: lane holds A[m=lane&15][k=kc*32+(lane>>4)*8+j] = one 16B load from node row.
// B-frag: pre-packed (k_cvt) so lane's load is Wp[(ct*KC+kc)*64+lane] - coalesced.
// D: col=lane&15, row=(lane>>4)*4+reg (verified m89/m91). Writeback guarded; A-row
// overreads (node>=N, k>=K) hit finite poison multiplied by zero-padded B -> 0.
// #pragma unroll 1 on kc bounds live B-frags (R6 spill lesson).
template <int K, int KC, int OUT, int CT, bool RELU, bool BIAS>
__global__ __launch_bounds__(256) void k_gemm(const __hip_bfloat16* __restrict__ X, int xs,
                                              __hip_bfloat16* __restrict__ Y, int ys,
                                              const short8* __restrict__ Wp,
                                              const float* __restrict__ bias, int N) {
    const int lane = threadIdx.x & 63;
    const int wid = threadIdx.x >> 6;
    const int m0 = blockIdx.x * 64 + wid * 16;
    const int mrow = lane & 15;
    const int koct = lane >> 4;
    const __hip_bfloat16* xrow = X + (ll)(m0 + mrow) * xs + koct * 8;
    f32x4 acc[CT];
#pragma unroll
    for (int ct = 0; ct < CT; ++ct)
#pragma unroll
        for (int r = 0; r < 4; ++r) acc[ct][r] = 0.0f;
    float bv[CT];
#pragma unroll
    for (int ct = 0; ct < CT; ++ct) {
        int col = ct * 16 + mrow;
        bv[ct] = (BIAS && col < OUT) ? bias[col] : 0.0f;
    }
#pragma unroll 1
    for (int kc = 0; kc < KC; ++kc) {
        short8 a = *(const short8*)(xrow + kc * 32);
#pragma unroll
        for (int ct = 0; ct < CT; ++ct) {
            short8 b = Wp[(ct * KC + kc) * 64 + lane];
            acc[ct] = __builtin_amdgcn_mfma_f32_16x16x32_bf16(a, b, acc[ct], 0, 0, 0);
        }
    }
#pragma unroll
    for (int ct = 0; ct < CT; ++ct) {
        int col = ct * 16 + mrow;
        if (col >= OUT) continue;
#pragma unroll
        for (int r = 0; r < 4; ++r) {
            int node = m0 + koct * 4 + r;
            if (node >= N) continue;
            float v = acc[ct][r] + bv[ct];
            if (RELU) v = fmaxf(v, 0.0f);
            Y[(ll)node * ys + col] = __float2bfloat16(v);
        }
    }
}

// ---------------- pool: segment-max of zbuf into pooled (hierarchical) ----------------
__global__ void k_pool(const float* __restrict__ zb, const int* __restrict__ batch,
                       unsigned* __restrict__ pooled, const int* __restrict__ flags, int N) {
    __shared__ unsigned lmax[192];
    int wi = flags[1];
    for (int i = threadIdx.x; i < 192; i += blockDim.x) lmax[i] = ENC_NEG_INF;
    __syncthreads();
    int n = blockIdx.x * blockDim.x + threadIdx.x;
    int lane = threadIdx.x & 63;
    float z0 = -3.4e38f, z1 = -3.4e38f, z2 = -3.4e38f;
    int g = 0;
    if (n < N) {
        z0 = zb[(ll)n * 3 + 0];
        z1 = zb[(ll)n * 3 + 1];
        z2 = zb[(ll)n * 3 + 2];
        g = ldi(batch, n, wi);
    }
    int g0 = __shfl(g, 0);
    unsigned long long uni = __ballot(n < N && g == g0);
    if (uni == ~0ULL) {
#pragma unroll
        for (int off = 32; off > 0; off >>= 1) {
            z0 = fmaxf(z0, __shfl_xor(z0, off));
            z1 = fmaxf(z1, __shfl_xor(z1, off));
            z2 = fmaxf(z2, __shfl_xor(z2, off));
        }
        if (lane == 0) {
            atomicMax(&lmax[g0 * 3 + 0], fenc(z0));
            atomicMax(&lmax[g0 * 3 + 1], fenc(z1));
            atomicMax(&lmax[g0 * 3 + 2], fenc(z2));
        }
    } else if (n < N) {
        atomicMax(&lmax[g * 3 + 0], fenc(z0));
        atomicMax(&lmax[g * 3 + 1], fenc(z1));
        atomicMax(&lmax[g * 3 + 2], fenc(z2));
    }
    __syncthreads();
    for (int i = threadIdx.x; i < 192; i += blockDim.x) {
        unsigned v = lmax[i];
        if (v != ENC_NEG_INF) atomicMax(&pooled[i], v);
    }
}

// ---------------- softmax over [64,3] ----------------
__global__ void k_softmax(const unsigned* __restrict__ pooled, void* __restrict__ out,
                          const int* __restrict__ flags) {
    int g = threadIdx.x;
    if (g >= 64) return;
    int bf = flags[0];
    float a = fdec(pooled[g * 3 + 0]);
    float b = fdec(pooled[g * 3 + 1]);
    float c = fdec(pooled[g * 3 + 2]);
    float m = fmaxf(a, fmaxf(b, c));
    float ea = __expf(a - m), eb = __expf(b - m), ec = __expf(c - m);
    float s = 1.0f / (ea + eb + ec);
    if (bf) {
        __hip_bfloat16* o = (__hip_bfloat16*)out;
        o[g * 3 + 0] = __float2bfloat16(ea * s);
        o[g * 3 + 1] = __float2bfloat16(eb * s);
        o[g * 3 + 2] = __float2bfloat16(ec * s);
    } else {
        float* o = (float*)out;
        o[g * 3 + 0] = ea * s;
        o[g * 3 + 1] = eb * s;
        o[g * 3 + 2] = ec * s;
    }
}

extern "C" void kernel_launch(void* const* d_in, const int* in_sizes, int n_in,
                              void* d_out, int out_size, void* d_ws, size_t ws_size,
                              hipStream_t stream) {
    const void* x = d_in[0];
    const int* ei = (const int*)d_in[1];
    const int* batch = (const int*)d_in[2];

    const int N = in_sizes[0] / 36;
    const int E = in_sizes[1] / 2;

    // ---- workspace carve ----
    char* ws = (char*)d_ws;
    size_t off = 0;
    auto carve = [&](size_t bytes) {
        char* p = ws + off;
        off = (off + bytes + 255) & ~(size_t)255;
        return p;
    };
    int* flags = (int*)carve(16);
    float* wfm = (float*)carve((size_t)N_MISC * 4);
    __hip_bfloat16* wpack = (__hip_bfloat16*)carve((size_t)N_PACK * 2);
    float* dinv = (float*)carve((size_t)N * 4);
    int* cnt = (int*)carve((size_t)N * 4);
    int* rowptr = (int*)carve((size_t)(N + 1) * 4);
    int2* ep = (int2*)carve((size_t)E * 8);
    unsigned* pooled = (unsigned*)carve(768);
    const int NB = DIV_UP(N + 1, 256);
    int* bsum = (int*)carve((size_t)NB * 4);
    float* zbuf = (float*)carve((size_t)N * 12);
    // R1: A1 bf16 s64 (128B) | A2 bf16 s96 (192B) | T3 bf16 s64 (128B)
    char* R1 = carve((size_t)N * 192);
    // R2: H1 bf16 s80 (160B) | H2 bf16 s160 (320B)
    char* R2 = carve((size_t)N * 320);
    (void)carve(65536);  // pad: unguarded GEMM A-row overreads stay in workspace

    const int B = 256;
    const int GB = DIV_UP(N, 64);

    // 0. dtype detection (+cnt zero) + weight conversion/packing
    k_detect<<<DIV_UP(N, B), B, 0, stream>>>((const unsigned*)x, (const unsigned*)ei, flags, cnt,
                                             N);
    k_cvt<<<DIV_UP(N_PACK + N_MISC, B), B, 0, stream>>>(d_in[3], d_in[4], d_in[5], d_in[6],
                                                        d_in[7], d_in[8], d_in[9], d_in[10], wpack,
                                                        wfm, flags);

    // 1. CSR build
    k_hist<<<DIV_UP(E, B), B, 0, stream>>>(ei, cnt, flags, E);
    k_scan1<<<NB, 256, 0, stream>>>(cnt, bsum, dinv, N);
    k_scan2<<<1, 256, 0, stream>>>(bsum, NB, pooled);
    k_scan3<<<NB, 256, 0, stream>>>(cnt, bsum, rowptr, N);
    k_fill<<<DIV_UP(E, B), B, 0, stream>>>(ei, rowptr, cnt, ep, dinv, flags, E);

    // 2. layer 1: agg x (36) -> A1 bf16 s64; MFMA GEMM 36->75 relu -> H1 bf16 s80
    k_agg<<<DIV_UP(N, 4), B, 0, stream>>>(x, 36, (__hip_bfloat16*)R1, 64, 36, rowptr, ep, dinv,
                                          flags, N);
    k_gemm<36, 2, 75, 5, true, true><<<GB, B, 0, stream>>>(
        (const __hip_bfloat16*)R1, 64, (__hip_bfloat16*)R2, 80, (const short8*)(wpack + P1),
        wfm + MB1, N);

    // 3. layer 2: agg H1 (75, paired) -> A2 bf16 s96; MFMA GEMM 75->150 relu -> H2 bf16 s160
    k_aggp<<<DIV_UP(N, 4), B, 0, stream>>>((const __hip_bfloat16*)R2, 80, (__hip_bfloat16*)R1, 96,
                                           38, rowptr, ep, dinv, N);
    k_gemm<75, 3, 150, 10, true, true><<<GB, B, 0, stream>>>(
        (const __hip_bfloat16*)R1, 96, (__hip_bfloat16*)R2, 160, (const short8*)(wpack + P2),
        wfm + MB2, N);

    // 4. layer 3: MFMA GEMM 150->50 -> T3 bf16 s64; fused agg+head -> zbuf[N,3]
    k_gemm<150, 5, 50, 4, false, false><<<GB, B, 0, stream>>>(
        (const __hip_bfloat16*)R2, 160, (__hip_bfloat16*)R1, 64, (const short8*)(wpack + P3), wfm,
        N);
    k_agg3h<<<DIV_UP(N, 4), B, 0, stream>>>((const __hip_bfloat16*)R1, 64, zbuf, rowptr, ep, dinv,
                                            wfm, N);

    // 5. pooling + softmax
    k_pool<<<DIV_UP(N, B), B, 0, stream>>>(zbuf, batch, pooled, flags, N);
    k_softmax<<<1, 64, 0, stream>>>(pooled, d_out, flags);
}

// Round 13
// 238.507 us; speedup vs baseline: 1.6333x; 1.0682x over previous
//
#include <hip/hip_runtime.h>
#include <hip/hip_bf16.h>

#define DIV_UP(a, b) (((a) + (b) - 1) / (b))
typedef long long ll;
typedef __attribute__((ext_vector_type(8))) short short8;
typedef __attribute__((ext_vector_type(4))) float f32x4;

// ---------- runtime-dtype helpers ----------
__device__ __forceinline__ float ldf(const void* p, ll i, int bf) {
    return bf ? __bfloat162float(((const __hip_bfloat16*)p)[i]) : ((const float*)p)[i];
}
__device__ __forceinline__ int ldi(const int* p, ll i, int w) {
    return w ? p[2 * i] : p[i];
}
// decode packed bf16 pair (little-endian: low 16 bits = even col)
__device__ __forceinline__ void bf16pair(unsigned u, float& f0, float& f1) {
    f0 = __uint_as_float(u << 16);
    f1 = __uint_as_float(u & 0xFFFF0000u);
}

// ---- ordered-uint encoding for float atomicMax ----
__device__ __forceinline__ unsigned fenc(float f) {
    unsigned u = __float_as_uint(f);
    return (u & 0x80000000u) ? ~u : (u | 0x80000000u);
}
__device__ __forceinline__ float fdec(unsigned u) {
    unsigned v = (u & 0x80000000u) ? (u & 0x7FFFFFFFu) : ~u;
    return __uint_as_float(v);
}
#define ENC_NEG_INF 0x007FFFFFu

// ---- f32 misc pool offsets ----
#define MB1 0    // b1: 75
#define MB2 80   // b2: 150
#define MHW 240  // Wo: 150
#define MB3 390  // b3: 50
#define MBO 440  // bo: 3
#define N_MISC 444
// ---- Wpack (bf16, B-fragment layout) region bases, in bf16 elements ----
#define P1 0      // L1: CT=5, KC=2 -> 5120
#define P2 5120   // L2: CT=10, KC=3 -> 15360
#define P3 20480  // L3: CT=4, KC=5 -> 10240
#define N_PACK 30720

// ---------------- dtype detection + cnt zero (fused, grid-wide) ----------------
__global__ void k_detect(const unsigned* __restrict__ xb, const unsigned* __restrict__ eb,
                         int* __restrict__ flags, int* __restrict__ cnt, int N) {
    int idx = blockIdx.x * 256 + threadIdx.x;
    if (idx < N) cnt[idx] = 0;
    if (blockIdx.x != 0) return;
    __shared__ int sv[2];
    int t = threadIdx.x;
    if (t < 2) sv[t] = 0;
    __syncthreads();
    unsigned e = (xb[t] >> 7) & 0xFFu;
    int vote = (e >= 115u && e <= 133u) ? 1 : 0;
    int zero = (eb[2 * t + 1] == 0u) ? 1 : 0;
    atomicAdd(&sv[0], vote);
    atomicAdd(&sv[1], zero);
    __syncthreads();
    if (t == 0) {
        flags[0] = (sv[0] > 128) ? 1 : 0;
        flags[1] = (sv[1] > 200) ? 1 : 0;
    }
}

// ---------------- weight conversion: MFMA B-fragment pack + misc f32 pool (fused) ---------
__global__ void k_cvt(const void* __restrict__ W1, const void* __restrict__ b1,
                      const void* __restrict__ W2, const void* __restrict__ b2,
                      const void* __restrict__ W3, const void* __restrict__ b3,
                      const void* __restrict__ Wo, const void* __restrict__ bo,
                      __hip_bfloat16* __restrict__ wp, float* __restrict__ wfm,
                      const int* __restrict__ flags) {
    int t = blockIdx.x * blockDim.x + threadIdx.x;
    int bf = flags[0];
    if (t < N_PACK) {
        const void* W;
        int i, K, OUT, KC;
        if (t < P2) {
            W = W1;
            i = t;
            K = 36;
            OUT = 75;
            KC = 2;
        } else if (t < P3) {
            W = W2;
            i = t - P2;
            K = 75;
            OUT = 150;
            KC = 3;
        } else {
            W = W3;
            i = t - P3;
            K = 150;
            OUT = 50;
            KC = 5;
        }
        int j = i & 7;
        int lane = (i >> 3) & 63;
        int tile = i >> 9;
        int kc = tile % KC;
        int ct = tile / KC;
        int k = kc * 32 + ((lane >> 4) << 3) + j;
        int col = ct * 16 + (lane & 15);
        float v = (k < K && col < OUT) ? ldf(W, (ll)k * OUT + col, bf) : 0.0f;
        wp[t] = __float2bfloat16(v);
    } else {
        int m = t - N_PACK;
        if (m >= N_MISC) return;
        float v = 0.0f;
        if (m < 75)
            v = ldf(b1, m, bf);
        else if (m >= MB2 && m < MB2 + 150)
            v = ldf(b2, m - MB2, bf);
        else if (m >= MHW && m < MHW + 150)
            v = ldf(Wo, m - MHW, bf);
        else if (m >= MB3 && m < MB3 + 50)
            v = ldf(b3, m - MB3, bf);
        else if (m >= MBO && m < MBO + 3)
            v = ldf(bo, m - MBO, bf);
        wfm[m] = v;
    }
}

// ---------------- CSR build ----------------
__global__ void k_hist(const int* __restrict__ ei, int* __restrict__ cnt,
                       const int* __restrict__ flags, int E) {
    int t = blockIdx.x * blockDim.x + threadIdx.x;
    if (t >= E) return;
    atomicAdd(&cnt[ldi(ei, (ll)E + t, flags[1])], 1);
}
__global__ void k_scan1(const int* __restrict__ cnt, int* __restrict__ bsum,
                        float* __restrict__ dinv, int N) {
    __shared__ int s[256];
    int t = threadIdx.x;
    int idx = blockIdx.x * 256 + t;
    int v = (idx < N) ? cnt[idx] : 0;
    if (idx < N) dinv[idx] = rsqrtf((float)v + 1.0f);  // +1 self-loop
    s[t] = v;
    __syncthreads();
#pragma unroll
    for (int off = 128; off > 0; off >>= 1) {
        if (t < off) s[t] += s[t + off];
        __syncthreads();
    }
    if (t == 0) bsum[blockIdx.x] = s[0];
}
// single-block scan of bsum; also inits pooled (fused - runs long before k_pool)
__global__ void k_scan2(int* __restrict__ bsum, int nb, unsigned* __restrict__ pooled) {
    __shared__ int s[256];
    int t = threadIdx.x;
    if (t < 192) pooled[t] = ENC_NEG_INF;
    int run = 0;
    for (int base = 0; base < nb; base += 256) {
        int i = base + t;
        int v = (i < nb) ? bsum[i] : 0;
        s[t] = v;
        __syncthreads();
        for (int off = 1; off < 256; off <<= 1) {
            int o = (t >= off) ? s[t - off] : 0;
            __syncthreads();
            s[t] += o;
            __syncthreads();
        }
        if (i < nb) bsum[i] = run + s[t] - v;
        run += s[255];
        __syncthreads();
    }
}
// per-block local scan + offset -> rowptr; re-zeroes cnt for use as k_fill cursor (fused)
__global__ void k_scan3(int* __restrict__ cnt, const int* __restrict__ bsum,
                        int* __restrict__ rowptr, int N) {
    __shared__ int s[256];
    int t = threadIdx.x;
    int idx = blockIdx.x * 256 + t;
    int v = (idx < N) ? cnt[idx] : 0;
    if (idx < N) cnt[idx] = 0;
    s[t] = v;
    __syncthreads();
    for (int off = 1; off < 256; off <<= 1) {
        int o = (t >= off) ? s[t - off] : 0;
        __syncthreads();
        s[t] += o;
        __syncthreads();
    }
    if (idx <= N) rowptr[idx] = bsum[blockIdx.x] + s[t] - v;
}
__global__ void k_fill(const int* __restrict__ ei, const int* __restrict__ rowptr,
                       int* __restrict__ cursor, int2* __restrict__ ep,
                       const float* __restrict__ dinv, const int* __restrict__ flags, int E) {
    int t = blockIdx.x * blockDim.x + threadIdx.x;
    if (t >= E) return;
    int wi = flags[1];
    int s = ldi(ei, t, wi);
    int d = ldi(ei, (ll)E + t, wi);
    int pos = rowptr[d] + atomicAdd(&cursor[d], 1);
    int2 v;
    v.x = s;
    v.y = __float_as_int(dinv[s] * dinv[d]);
    ep[pos] = v;
}

// ---------------- layer-1 aggregation: TWO nodes per wave (half-wave = 32 lanes) ----------
// x is N x 36 (runtime dtype). bf16 path: 18 pair-lanes; f32 path: 32 lanes + lanes 0-3 carry
// cols 32-35. Per-column accumulation order identical to wave-per-node version (bit-exact).
__global__ void k_agg1(const void* __restrict__ X, __hip_bfloat16* __restrict__ Y,
                       const int* __restrict__ rowptr, const int2* __restrict__ ep,
                       const float* __restrict__ dinv, const int* __restrict__ flags, int N) {
    int n = blockIdx.x * 8 + (threadIdx.x >> 5);
    if (n >= N) return;
    int lane = threadIdx.x & 31;
    int bf = flags[0];
    float di = dinv[n];
    float w0 = di * di;
    int j = rowptr[n];
    int je = rowptr[n + 1];
    if (bf) {
        const __hip_bfloat16* Xb = (const __hip_bfloat16*)X;
        bool act = lane < 18;
        float a0 = 0.0f, a1 = 0.0f;
        if (act) {
            float f0, f1;
            bf16pair(*(const unsigned*)(Xb + (ll)n * 36 + 2 * lane), f0, f1);
            a0 = w0 * f0;
            a1 = w0 * f1;
        }
        for (; j + 3 < je; j += 4) {
            int2 v0 = ep[j];
            int2 v1 = ep[j + 1];
            int2 v2 = ep[j + 2];
            int2 v3 = ep[j + 3];
            if (act) {
                float f0, f1;
                bf16pair(*(const unsigned*)(Xb + (ll)v0.x * 36 + 2 * lane), f0, f1);
                float wa = __int_as_float(v0.y);
                a0 = fmaf(wa, f0, a0);
                a1 = fmaf(wa, f1, a1);
                bf16pair(*(const unsigned*)(Xb + (ll)v1.x * 36 + 2 * lane), f0, f1);
                wa = __int_as_float(v1.y);
                a0 = fmaf(wa, f0, a0);
                a1 = fmaf(wa, f1, a1);
                bf16pair(*(const unsigned*)(Xb + (ll)v2.x * 36 + 2 * lane), f0, f1);
                wa = __int_as_float(v2.y);
                a0 = fmaf(wa, f0, a0);
                a1 = fmaf(wa, f1, a1);
                bf16pair(*(const unsigned*)(Xb + (ll)v3.x * 36 + 2 * lane), f0, f1);
                wa = __int_as_float(v3.y);
                a0 = fmaf(wa, f0, a0);
                a1 = fmaf(wa, f1, a1);
            }
        }
        for (; j < je; ++j) {
            int2 v0 = ep[j];
            if (act) {
                float f0, f1;
                bf16pair(*(const unsigned*)(Xb + (ll)v0.x * 36 + 2 * lane), f0, f1);
                float wa = __int_as_float(v0.y);
                a0 = fmaf(wa, f0, a0);
                a1 = fmaf(wa, f1, a1);
            }
        }
        if (act) {
            __hip_bfloat162 h;
            h.x = __float2bfloat16(a0);
            h.y = __float2bfloat16(a1);
            *(__hip_bfloat162*)(Y + (ll)n * 64 + 2 * lane) = h;
        }
    } else {
        const float* Xf = (const float*)X;
        bool act2 = lane < 4;
        float a0 = w0 * Xf[(ll)n * 36 + lane];
        float a1 = act2 ? w0 * Xf[(ll)n * 36 + 32 + lane] : 0.0f;
        for (; j + 3 < je; j += 4) {
            int2 v0 = ep[j];
            int2 v1 = ep[j + 1];
            int2 v2 = ep[j + 2];
            int2 v3 = ep[j + 3];
            float wa = __int_as_float(v0.y);
            a0 = fmaf(wa, Xf[(ll)v0.x * 36 + lane], a0);
            if (act2) a1 = fmaf(wa, Xf[(ll)v0.x * 36 + 32 + lane], a1);
            wa = __int_as_float(v1.y);
            a0 = fmaf(wa, Xf[(ll)v1.x * 36 + lane], a0);
            if (act2) a1 = fmaf(wa, Xf[(ll)v1.x * 36 + 32 + lane], a1);
            wa = __int_as_float(v2.y);
            a0 = fmaf(wa, Xf[(ll)v2.x * 36 + lane], a0);
            if (act2) a1 = fmaf(wa, Xf[(ll)v2.x * 36 + 32 + lane], a1);
            wa = __int_as_float(v3.y);
            a0 = fmaf(wa, Xf[(ll)v3.x * 36 + lane], a0);
            if (act2) a1 = fmaf(wa, Xf[(ll)v3.x * 36 + 32 + lane], a1);
        }
        for (; j < je; ++j) {
            int2 v0 = ep[j];
            float wa = __int_as_float(v0.y);
            a0 = fmaf(wa, Xf[(ll)v0.x * 36 + lane], a0);
            if (act2) a1 = fmaf(wa, Xf[(ll)v0.x * 36 + 32 + lane], a1);
        }
        Y[(ll)n * 64 + lane] = __float2bfloat16(a0);
        if (act2) Y[(ll)n * 64 + 32 + lane] = __float2bfloat16(a1);
    }
}

// ---------------- layer-2 paired aggregation: TWO nodes per wave ----------------
// CP=38 pairs over 32 lanes: lane carries pair `lane`; lanes 0-5 also carry pair 32+lane.
__global__ void k_aggp2(const __hip_bfloat16* __restrict__ X, int xs,
                        __hip_bfloat16* __restrict__ Y, int ys, const int* __restrict__ rowptr,
                        const int2* __restrict__ ep, const float* __restrict__ dinv, int N) {
    int n = blockIdx.x * 8 + (threadIdx.x >> 5);
    if (n >= N) return;
    int lane = threadIdx.x & 31;
    bool act2 = lane < 6;  // pairs 32..37
    float di = dinv[n];
    float w0 = di * di;
    float a0, a1, b0 = 0.0f, b1 = 0.0f;
    {
        float f0, f1;
        bf16pair(*(const unsigned*)(X + (ll)n * xs + 2 * lane), f0, f1);
        a0 = w0 * f0;
        a1 = w0 * f1;
        if (act2) {
            bf16pair(*(const unsigned*)(X + (ll)n * xs + 64 + 2 * lane), f0, f1);
            b0 = w0 * f0;
            b1 = w0 * f1;
        }
    }
    int j = rowptr[n];
    int je = rowptr[n + 1];
    for (; j + 1 < je; j += 2) {
        int2 v0 = ep[j];
        int2 v1 = ep[j + 1];
        float wa = __int_as_float(v0.y), wb = __int_as_float(v1.y);
        float f0, f1;
        bf16pair(*(const unsigned*)(X + (ll)v0.x * xs + 2 * lane), f0, f1);
        a0 = fmaf(wa, f0, a0);
        a1 = fmaf(wa, f1, a1);
        bf16pair(*(const unsigned*)(X + (ll)v1.x * xs + 2 * lane), f0, f1);
        a0 = fmaf(wb, f0, a0);
        a1 = fmaf(wb, f1, a1);
        if (act2) {
            bf16pair(*(const unsigned*)(X + (ll)v0.x * xs + 64 + 2 * lane), f0, f1);
            b0 = fmaf(wa, f0, b0);
            b1 = fmaf(wa, f1, b1);
            bf16pair(*(const unsigned*)(X + (ll)v1.x * xs + 64 + 2 * lane), f0, f1);
            b0 = fmaf(wb, f0, b0);
            b1 = fmaf(wb, f1, b1);
        }
    }
    if (j < je) {
        int2 v0 = ep[j];
        float wa = __int_as_float(v0.y);
        float f0, f1;
        bf16pair(*(const unsigned*)(X + (ll)v0.x * xs + 2 * lane), f0, f1);
        a0 = fmaf(wa, f0, a0);
        a1 = fmaf(wa, f1, a1);
        if (act2) {
            bf16pair(*(const unsigned*)(X + (ll)v0.x * xs + 64 + 2 * lane), f0, f1);
            b0 = fmaf(wa, f0, b0);
            b1 = fmaf(wa, f1, b1);
        }
    }
    __hip_bfloat162 h;
    h.x = __float2bfloat16(a0);
    h.y = __float2bfloat16(a1);
    *(__hip_bfloat162*)(Y + (ll)n * ys + 2 * lane) = h;
    if (act2) {
        h.x = __float2bfloat16(b0);
        h.y = __float2bfloat16(b1);
        *(__hip_bfloat162*)(Y + (ll)n * ys + 64 + 2 * lane) = h;
    }
}

// ---------------- fused layer-3 aggregation + head: TWO nodes per wave ----------------
// half-wave = 32 lanes per node; CP=25 pairs; shuffle-reduce offsets 16..1 stay in-half.
__global__ void k_agg3h(const __hip_bfloat16* __restrict__ X, int xs, float* __restrict__ zb,
                        const int* __restrict__ rowptr, const int2* __restrict__ ep,
                        const float* __restrict__ dinv, const float* __restrict__ wfm, int N) {
    int n = blockIdx.x * 8 + (threadIdx.x >> 5);
    if (n >= N) return;
    int lane = threadIdx.x & 31;
    bool act = lane < 25;
    int c0 = 2 * lane;
    float w00 = 0, w01 = 0, w02 = 0, w10 = 0, w11 = 0, w12 = 0, bb0 = 0, bb1 = 0;
    if (act) {
        w00 = wfm[MHW + c0 * 3 + 0];
        w01 = wfm[MHW + c0 * 3 + 1];
        w02 = wfm[MHW + c0 * 3 + 2];
        w10 = wfm[MHW + c0 * 3 + 3];
        w11 = wfm[MHW + c0 * 3 + 4];
        w12 = wfm[MHW + c0 * 3 + 5];
        bb0 = wfm[MB3 + c0];
        bb1 = wfm[MB3 + c0 + 1];
    }
    float di = dinv[n];
    float w0 = di * di;
    float a0 = 0.0f, a1 = 0.0f;
    if (act) {
        float f0, f1;
        bf16pair(*(const unsigned*)(X + (ll)n * xs + 2 * lane), f0, f1);
        a0 = w0 * f0;
        a1 = w0 * f1;
    }
    int j = rowptr[n];
    int je = rowptr[n + 1];
    for (; j + 3 < je; j += 4) {
        int2 v0 = ep[j];
        int2 v1 = ep[j + 1];
        int2 v2 = ep[j + 2];
        int2 v3 = ep[j + 3];
        if (act) {
            float f0, f1;
            bf16pair(*(const unsigned*)(X + (ll)v0.x * xs + 2 * lane), f0, f1);
            float wa = __int_as_float(v0.y);
            a0 = fmaf(wa, f0, a0);
            a1 = fmaf(wa, f1, a1);
            bf16pair(*(const unsigned*)(X + (ll)v1.x * xs + 2 * lane), f0, f1);
            wa = __int_as_float(v1.y);
            a0 = fmaf(wa, f0, a0);
            a1 = fmaf(wa, f1, a1);
            bf16pair(*(const unsigned*)(X + (ll)v2.x * xs + 2 * lane), f0, f1);
            wa = __int_as_float(v2.y);
            a0 = fmaf(wa, f0, a0);
            a1 = fmaf(wa, f1, a1);
            bf16pair(*(const unsigned*)(X + (ll)v3.x * xs + 2 * lane), f0, f1);
            wa = __int_as_float(v3.y);
            a0 = fmaf(wa, f0, a0);
            a1 = fmaf(wa, f1, a1);
        }
    }
    for (; j < je; ++j) {
        int2 v0 = ep[j];
        if (act) {
            float f0, f1;
            bf16pair(*(const unsigned*)(X + (ll)v0.x * xs + 2 * lane), f0, f1);
            float wa = __int_as_float(v0.y);
            a0 = fmaf(wa, f0, a0);
            a1 = fmaf(wa, f1, a1);
        }
    }
    float h0 = act ? fmaxf(a0 + bb0, 0.0f) : 0.0f;
    float h1 = act ? fmaxf(a1 + bb1, 0.0f) : 0.0f;
    float z0 = h0 * w00 + h1 * w10;
    float z1 = h0 * w01 + h1 * w11;
    float z2 = h0 * w02 + h1 * w12;
#pragma unroll
    for (int off = 16; off > 0; off >>= 1) {
        z0 += __shfl_xor(z0, off);
        z1 += __shfl_xor(z1, off);
        z2 += __shfl_xor(z2, off);
    }
    if (lane == 0) {
        zb[(ll)n * 3 + 0] = z0 + wfm[MBO + 0];
        zb[(ll)n * 3 + 1] = z1 + wfm[MBO + 1];
        zb[(ll)n * 3 + 2] = z2 + wfm[MBO + 2];
    }
}

// ---------------- MFMA GEMM: Y = act(X @ W + b), X bf16 row-major (stride >= KC*32) -------
// wave = 16 nodes x OUT cols via mfma_f32_16x16x32_bf16. No LDS, no in-loop SMEM.
// B-frag pre-packed (k_cvt); D: col=lane&15, row=(lane>>4)*4+reg. Writeback guarded; A-row
// overreads hit finite poison x zero-padded B -> 0. #pragma unroll 1 bounds live B-frags.
template <int K, int KC, int OUT, int CT, bool RELU, bool BIAS>
__global__ __launch_bounds__(256) void k_gemm(const __hip_bfloat16* __restrict__ X, int xs,
                                              __hip_bfloat16* __restrict__ Y, int ys,
                                              const short8* __restrict__ Wp,
                                              const float* __restrict__ bias, int N) {
    const int lane = threadIdx.x & 63;
    const int wid = threadIdx.x >> 6;
    const int m0 = blockIdx.x * 64 + wid * 16;
    const int mrow = lane & 15;
    const int koct = lane >> 4;
    const __hip_bfloat16* xrow = X + (ll)(m0 + mrow) * xs + koct * 8;
    f32x4 acc[CT];
#pragma unroll
    for (int ct = 0; ct < CT; ++ct)
#pragma unroll
        for (int r = 0; r < 4; ++r) acc[ct][r] = 0.0f;
    float bv[CT];
#pragma unroll
    for (int ct = 0; ct < CT; ++ct) {
        int col = ct * 16 + mrow;
        bv[ct] = (BIAS && col < OUT) ? bias[col] : 0.0f;
    }
#pragma unroll 1
    for (int kc = 0; kc < KC; ++kc) {
        short8 a = *(const short8*)(xrow + kc * 32);
#pragma unroll
        for (int ct = 0; ct < CT; ++ct) {
            short8 b = Wp[(ct * KC + kc) * 64 + lane];
            acc[ct] = __builtin_amdgcn_mfma_f32_16x16x32_bf16(a, b, acc[ct], 0, 0, 0);
        }
    }
#pragma unroll
    for (int ct = 0; ct < CT; ++ct) {
        int col = ct * 16 + mrow;
        if (col >= OUT) continue;
#pragma unroll
        for (int r = 0; r < 4; ++r) {
            int node = m0 + koct * 4 + r;
            if (node >= N) continue;
            float v = acc[ct][r] + bv[ct];
            if (RELU) v = fmaxf(v, 0.0f);
            Y[(ll)node * ys + col] = __float2bfloat16(v);
        }
    }
}

// ---------------- pool: segment-max of zbuf into pooled (hierarchical) ----------------
__global__ void k_pool(const float* __restrict__ zb, const int* __restrict__ batch,
                       unsigned* __restrict__ pooled, const int* __restrict__ flags, int N) {
    __shared__ unsigned lmax[192];
    int wi = flags[1];
    for (int i = threadIdx.x; i < 192; i += blockDim.x) lmax[i] = ENC_NEG_INF;
    __syncthreads();
    int n = blockIdx.x * blockDim.x + threadIdx.x;
    int lane = threadIdx.x & 63;
    float z0 = -3.4e38f, z1 = -3.4e38f, z2 = -3.4e38f;
    int g = 0;
    if (n < N) {
        z0 = zb[(ll)n * 3 + 0];
        z1 = zb[(ll)n * 3 + 1];
        z2 = zb[(ll)n * 3 + 2];
        g = ldi(batch, n, wi);
    }
    int g0 = __shfl(g, 0);
    unsigned long long uni = __ballot(n < N && g == g0);
    if (uni == ~0ULL) {
#pragma unroll
        for (int off = 32; off > 0; off >>= 1) {
            z0 = fmaxf(z0, __shfl_xor(z0, off));
            z1 = fmaxf(z1, __shfl_xor(z1, off));
            z2 = fmaxf(z2, __shfl_xor(z2, off));
        }
        if (lane == 0) {
            atomicMax(&lmax[g0 * 3 + 0], fenc(z0));
            atomicMax(&lmax[g0 * 3 + 1], fenc(z1));
            atomicMax(&lmax[g0 * 3 + 2], fenc(z2));
        }
    } else if (n < N) {
        atomicMax(&lmax[g * 3 + 0], fenc(z0));
        atomicMax(&lmax[g * 3 + 1], fenc(z1));
        atomicMax(&lmax[g * 3 + 2], fenc(z2));
    }
    __syncthreads();
    for (int i = threadIdx.x; i < 192; i += blockDim.x) {
        unsigned v = lmax[i];
        if (v != ENC_NEG_INF) atomicMax(&pooled[i], v);
    }
}

// ---------------- softmax over [64,3] ----------------
__global__ void k_softmax(const unsigned* __restrict__ pooled, void* __restrict__ out,
                          const int* __restrict__ flags) {
    int g = threadIdx.x;
    if (g >= 64) return;
    int bf = flags[0];
    float a = fdec(pooled[g * 3 + 0]);
    float b = fdec(pooled[g * 3 + 1]);
    float c = fdec(pooled[g * 3 + 2]);
    float m = fmaxf(a, fmaxf(b, c));
    float ea = __expf(a - m), eb = __expf(b - m), ec = __expf(c - m);
    float s = 1.0f / (ea + eb + ec);
    if (bf) {
        __hip_bfloat16* o = (__hip_bfloat16*)out;
        o[g * 3 + 0] = __float2bfloat16(ea * s);
        o[g * 3 + 1] = __float2bfloat16(eb * s);
        o[g * 3 + 2] = __float2bfloat16(ec * s);
    } else {
        float* o = (float*)out;
        o[g * 3 + 0] = ea * s;
        o[g * 3 + 1] = eb * s;
        o[g * 3 + 2] = ec * s;
    }
}

extern "C" void kernel_launch(void* const* d_in, const int* in_sizes, int n_in,
                              void* d_out, int out_size, void* d_ws, size_t ws_size,
                              hipStream_t stream) {
    const void* x = d_in[0];
    const int* ei = (const int*)d_in[1];
    const int* batch = (const int*)d_in[2];

    const int N = in_sizes[0] / 36;
    const int E = in_sizes[1] / 2;

    // ---- workspace carve ----
    char* ws = (char*)d_ws;
    size_t off = 0;
    auto carve = [&](size_t bytes) {
        char* p = ws + off;
        off = (off + bytes + 255) & ~(size_t)255;
        return p;
    };
    int* flags = (int*)carve(16);
    float* wfm = (float*)carve((size_t)N_MISC * 4);
    __hip_bfloat16* wpack = (__hip_bfloat16*)carve((size_t)N_PACK * 2);
    float* dinv = (float*)carve((size_t)N * 4);
    int* cnt = (int*)carve((size_t)N * 4);
    int* rowptr = (int*)carve((size_t)(N + 1) * 4);
    int2* ep = (int2*)carve((size_t)E * 8);
    unsigned* pooled = (unsigned*)carve(768);
    const int NB = DIV_UP(N + 1, 256);
    int* bsum = (int*)carve((size_t)NB * 4);
    float* zbuf = (float*)carve((size_t)N * 12);
    // R1: A1 bf16 s64 (128B) | A2 bf16 s96 (192B) | T3 bf16 s64 (128B)
    char* R1 = carve((size_t)N * 192);
    // R2: H1 bf16 s80 (160B) | H2 bf16 s160 (320B)
    char* R2 = carve((size_t)N * 320);
    (void)carve(65536);  // pad: unguarded GEMM A-row overreads stay in workspace

    const int B = 256;
    const int GB = DIV_UP(N, 64);

    // 0. dtype detection (+cnt zero) + weight conversion/packing
    k_detect<<<DIV_UP(N, B), B, 0, stream>>>((const unsigned*)x, (const unsigned*)ei, flags, cnt,
                                             N);
    k_cvt<<<DIV_UP(N_PACK + N_MISC, B), B, 0, stream>>>(d_in[3], d_in[4], d_in[5], d_in[6],
                                                        d_in[7], d_in[8], d_in[9], d_in[10], wpack,
                                                        wfm, flags);

    // 1. CSR build
    k_hist<<<DIV_UP(E, B), B, 0, stream>>>(ei, cnt, flags, E);
    k_scan1<<<NB, 256, 0, stream>>>(cnt, bsum, dinv, N);
    k_scan2<<<1, 256, 0, stream>>>(bsum, NB, pooled);
    k_scan3<<<NB, 256, 0, stream>>>(cnt, bsum, rowptr, N);
    k_fill<<<DIV_UP(E, B), B, 0, stream>>>(ei, rowptr, cnt, ep, dinv, flags, E);

    // 2. layer 1: agg x (36, 2 nodes/wave) -> A1 bf16 s64; MFMA GEMM 36->75 relu -> H1 s80
    k_agg1<<<DIV_UP(N, 8), B, 0, stream>>>(x, (__hip_bfloat16*)R1, rowptr, ep, dinv, flags, N);
    k_gemm<36, 2, 75, 5, true, true><<<GB, B, 0, stream>>>(
        (const __hip_bfloat16*)R1, 64, (__hip_bfloat16*)R2, 80, (const short8*)(wpack + P1),
        wfm + MB1, N);

    // 3. layer 2: agg H1 (75 paired, 2 nodes/wave) -> A2 s96; MFMA GEMM 75->150 relu -> H2 s160
    k_aggp2<<<DIV_UP(N, 8), B, 0, stream>>>((const __hip_bfloat16*)R2, 80, (__hip_bfloat16*)R1, 96,
                                            rowptr, ep, dinv, N);
    k_gemm<75, 3, 150, 10, true, true><<<GB, B, 0, stream>>>(
        (const __hip_bfloat16*)R1, 96, (__hip_bfloat16*)R2, 160, (const short8*)(wpack + P2),
        wfm + MB2, N);

    // 4. layer 3: MFMA GEMM 150->50 -> T3 s64; fused agg+head (2 nodes/wave) -> zbuf[N,3]
    k_gemm<150, 5, 50, 4, false, false><<<GB, B, 0, stream>>>(
        (const __hip_bfloat16*)R2, 160, (__hip_bfloat16*)R1, 64, (const short8*)(wpack + P3), wfm,
        N);
    k_agg3h<<<DIV_UP(N, 8), B, 0, stream>>>((const __hip_bfloat16*)R1, 64, zbuf, rowptr, ep, dinv,
                                            wfm, N);

    // 5. pooling + softmax
    k_pool<<<DIV_UP(N, B), B, 0, stream>>>(zbuf, batch, pooled, flags, N);
    k_softmax<<<1, 64, 0, stream>>>(pooled, d_out, flags);
}